// Round 9
// baseline (518.043 us; speedup 1.0000x reference)
//
#include <hip/hip_runtime.h>
#include <hip/hip_bf16.h>
#include <cstdint>

#define DEV_INLINE __device__ __forceinline__

// problem constants
constexpr int N0n = 100000, N1n = 25000, N2n = 6250;
constexpr int E0n = 800000, E1n = 200000, E2n = 50000;
constexpr int NT  = N0n + N1n + N2n;     // 131250 concatenated node space
constexpr int ET  = E0n + E1n + E2n;     // 1050000 concatenated edge space
constexpr int Bn  = 2;

DEV_INLINE float lrelu(float x) { return x > 0.f ? x : 0.01f * x; }

// r9: everything bulk is bf16 now (x, W, V since r8; U this round — error adds
// in quadrature with existing sources, predicted absmax ~2.4e-3). Agg kernels
// keep fp32 accumulation. Block-uniform LDS-csr fast path removes per-edge
// bound-check VALU (CAP is >=50 sigma above the binomial edge-count mean).
DEV_INLINE ushort f2bf(float f) {
    uint32_t u = __builtin_bit_cast(uint32_t, f);
    u += 0x7FFFu + ((u >> 16) & 1u);       // round-to-nearest-even
    return (ushort)(u >> 16);
}
DEV_INLINE float bflo(uint32_t w) { return __builtin_bit_cast(float, w << 16); }
DEV_INLINE float bfhi(uint32_t w) { return __builtin_bit_cast(float, w & 0xFFFF0000u); }
DEV_INLINE uint32_t pack2(float a, float b) {
    return (uint32_t)f2bf(a) | ((uint32_t)f2bf(b) << 16);
}
DEV_INLINE void unpack_bf8(float* u, const uint4 w) {
    u[0] = bflo(w.x); u[1] = bfhi(w.x);
    u[2] = bflo(w.y); u[3] = bfhi(w.y);
    u[4] = bflo(w.z); u[5] = bfhi(w.z);
    u[6] = bflo(w.w); u[7] = bfhi(w.w);
}

// acc[k] += relu(u[k] + v[k]) for 8 bf16 channels packed in a uint4
DEV_INLINE void acc_bf8(float* acc, const float* u, const uint4 w) {
    acc[0] += fmaxf(u[0] + bflo(w.x), 0.f);
    acc[1] += fmaxf(u[1] + bfhi(w.x), 0.f);
    acc[2] += fmaxf(u[2] + bflo(w.y), 0.f);
    acc[3] += fmaxf(u[3] + bfhi(w.y), 0.f);
    acc[4] += fmaxf(u[4] + bflo(w.z), 0.f);
    acc[5] += fmaxf(u[5] + bfhi(w.z), 0.f);
    acc[6] += fmaxf(u[6] + bflo(w.w), 0.f);
    acc[7] += fmaxf(u[7] + bfhi(w.w), 0.f);
}

typedef short bf16x8 __attribute__((ext_vector_type(8)));
typedef float f32x4 __attribute__((ext_vector_type(4)));

// ---------------- CSR build (3 graphs concatenated), 4 edges/thread ----------------

constexpr int Q0 = E0n / 4, Q1 = E1n / 4, Q2 = E2n / 4;   // 200000 / 50000 / 12500
constexpr int QT = Q0 + Q1 + Q2;                           // 262500

__global__ __launch_bounds__(256) void k_deg_count(const int* __restrict__ g0,
                                                   const int* __restrict__ g1,
                                                   const int* __restrict__ g2,
                                                   int* __restrict__ deg) {
    const int q = blockIdx.x * 256 + threadIdx.x;
    int4 d; int mod_, nb_;
    if (q < Q0)            { d = *(const int4*)&g0[E0n + q * 4];            mod_ = N0n; nb_ = 0; }
    else if (q < Q0 + Q1)  { d = *(const int4*)&g1[E1n + (q - Q0) * 4];     mod_ = N1n; nb_ = N0n; }
    else if (q < QT)       { d = *(const int4*)&g2[E2n + (q - Q0 - Q1) * 4]; mod_ = N2n; nb_ = N0n + N1n; }
    else return;
    atomicAdd(&deg[nb_ + d.x % mod_], 1);
    atomicAdd(&deg[nb_ + d.y % mod_], 1);
    atomicAdd(&deg[nb_ + d.z % mod_], 1);
    atomicAdd(&deg[nb_ + d.w % mod_], 1);
}

constexpr int SCAN_CHUNK = 2048;
constexpr int NCHUNK = (NT + SCAN_CHUNK - 1) / SCAN_CHUNK;   // 65

__global__ __launch_bounds__(256) void k_scan1(const int* __restrict__ deg,
                                               int* __restrict__ out,
                                               int* __restrict__ partials) {
    __shared__ int sums[256];
    const int chunk = blockIdx.x, t = threadIdx.x;
    const int base = chunk * SCAN_CHUNK + t * 8;
    int v[8]; int s = 0;
#pragma unroll
    for (int i = 0; i < 8; i++) { int idx = base + i; v[i] = (idx < NT) ? deg[idx] : 0; s += v[i]; }
    int val = s;
    sums[t] = val; __syncthreads();
    for (int off = 1; off < 256; off <<= 1) {
        int y = (t >= off) ? sums[t - off] : 0;
        __syncthreads();
        val += y; sums[t] = val;
        __syncthreads();
    }
    const int excl = val - s;
    if (t == 255) partials[chunk] = val;
    int run = excl;
#pragma unroll
    for (int i = 0; i < 8; i++) { int idx = base + i; if (idx < NT) out[idx] = run; run += v[i]; }
}

// scan2 folded in: each block redundantly prefix-sums the 65 partials in LDS.
__global__ __launch_bounds__(256) void k_scan3(const int* __restrict__ partials,
                                               int* __restrict__ offsets) {
    __shared__ int s[NCHUNK];
    __shared__ int pre[NCHUNK + 1];
    const int t = threadIdx.x;
    if (t < NCHUNK) s[t] = partials[t];
    __syncthreads();
    if (t == 0) {
        int run = 0;
        for (int i = 0; i < NCHUNK; i++) { pre[i] = run; run += s[i]; }
        pre[NCHUNK] = run;
    }
    __syncthreads();
    const int idx = blockIdx.x * 256 + t;
    if (idx < NT) offsets[idx] += pre[idx / SCAN_CHUNK];
    if (idx == 0) offsets[NT] = pre[NCHUNK];   // == ET
}

// Partitioned fill (4 edges/thread): valid-unpool sources at segment front;
// cursor[] afterwards == per-node valid-source count (consumed by fused aggs).
__global__ __launch_bounds__(256) void k_csr_fill(const int* __restrict__ g0,
                                                  const int* __restrict__ g1,
                                                  const int* __restrict__ g2,
                                                  const int* __restrict__ offsets,
                                                  int* __restrict__ cursor,
                                                  int* __restrict__ bcur,
                                                  int* __restrict__ csr) {
    const int q = blockIdx.x * 256 + threadIdx.x;
    int4 sv, dv; int mod_, nb_, thr_;
    if (q < Q0) {
        sv = *(const int4*)&g0[q * 4]; dv = *(const int4*)&g0[E0n + q * 4];
        mod_ = N0n; nb_ = 0; thr_ = N1n;
    } else if (q < Q0 + Q1) {
        const int lq = q - Q0;
        sv = *(const int4*)&g1[lq * 4]; dv = *(const int4*)&g1[E1n + lq * 4];
        mod_ = N1n; nb_ = N0n; thr_ = N2n;
    } else if (q < QT) {
        const int lq = q - Q0 - Q1;
        sv = *(const int4*)&g2[lq * 4]; dv = *(const int4*)&g2[E2n + lq * 4];
        mod_ = N2n; nb_ = N0n + N1n; thr_ = N2n;   // src < N2n always -> front
    } else return;
    const int ss[4] = {sv.x, sv.y, sv.z, sv.w};
    const int dd[4] = {dv.x, dv.y, dv.z, dv.w};
#pragma unroll
    for (int i = 0; i < 4; i++) {
        const int src = ss[i] % mod_;
        const int gd = nb_ + dd[i] % mod_;
        const bool front = src < thr_;
        const int pos = front ? offsets[gd] + atomicAdd(&cursor[gd], 1)
                              : offsets[gd + 1] - 1 - atomicAdd(&bcur[gd], 1);
        if (pos >= 0 && pos < ET) csr[pos] = src;   // local src id
    }
}

// ---------------- weight prep: W[2K][COUT] fp32 -> Wt[2*COUT][K] bf16 ----------------

__global__ __launch_bounds__(256) void k_wprep(const float* W0, ushort* T0,
                                               const float* W1, ushort* T1,
                                               const float* W2, ushort* T2,
                                               const float* W3, ushort* T3,
                                               const float* W4, ushort* T4,
                                               const float* W5, ushort* T5,
                                               const float* W6, ushort* T6,
                                               const float* W7, ushort* T7) {
    constexpr int KS[8] = {128, 256, 64, 256, 128, 64, 128, 64};
    constexpr int CS[8] = {256, 64, 128, 128, 64, 64, 64, 64};
    const int set = blockIdx.x >> 5;          // 32 blocks / set
    const int blk = blockIdx.x & 31;
    const float* W; ushort* T;
    switch (set) {
        case 0: W = W0; T = T0; break;
        case 1: W = W1; T = T1; break;
        case 2: W = W2; T = T2; break;
        case 3: W = W3; T = T3; break;
        case 4: W = W4; T = T4; break;
        case 5: W = W5; T = T5; break;
        case 6: W = W6; T = T6; break;
        default: W = W7; T = T7; break;
    }
    const int K = KS[set], C = CS[set];
    const int tot = 2 * C * K;
    for (int idx = blk * 256 + threadIdx.x; idx < tot; idx += 32 * 256) {
        const int n = idx / K, k = idx % K;
        float v;
        if (n < C) v = W[(size_t)k * C + n] - W[(size_t)(K + k) * C + n];
        else       v = W[(size_t)(K + k) * C + (n - C)];
        T[idx] = f2bf(v);
    }
}

// ---------------- latent MLP: z -> x0 bf16 [N2*B, 128] ----------------

__global__ __launch_bounds__(256) void k_latent(const float* __restrict__ z,
                                                const float* __restrict__ W1,
                                                const float* __restrict__ b1,
                                                const float* __restrict__ W2,
                                                const float* __restrict__ b2,
                                                ushort* __restrict__ x0b) {
    __shared__ float col[64];
    const int t = threadIdx.x;
    const int b = t >> 7, l = t & 127;
    const float zv = z[b * 128 + l];
    float h1[64];
#pragma unroll
    for (int k = 0; k < 64; k++) h1[k] = lrelu(zv * W1[k] + b1[k]);
    for (int nn = 0; nn < 8; nn++) {
        const int n = blockIdx.x * 8 + nn;
        if (n >= N2n) break;                 // uniform across block
        if (t < 64) col[t] = W2[t * N2n + n];
        __syncthreads();
        float s = b2[n];
#pragma unroll
        for (int k = 0; k < 64; k++) s += h1[k] * col[k];
        x0b[((size_t)n * Bn + b) * 128 + l] = f2bf(s);
        __syncthreads();
    }
}

// ---------------- MFMA GEMM: D = x_bf @ [Wd | Wb]; U bf16 (+bias), V bf16 ----------
// 4 waves = 2x2 wave grid; wave = 32x32 via 2x2 mfma_f32_16x16x32_bf16 frags.

template <int K, int COUT>
__global__ __launch_bounds__(256) void k_gemm_mfma(const ushort* __restrict__ xb,
                                                   const ushort* __restrict__ Wt,
                                                   const float* __restrict__ bias,
                                                   ushort* __restrict__ Ub,
                                                   ushort* __restrict__ Vb,
                                                   int Mrows) {
    constexpr int BM = 64;
    __shared__ ushort As[64][40];
    const int t = threadIdx.x;
    const int lane = t & 63;
    const int wave = t >> 6;
    const int wr = wave >> 1, wc = wave & 1;
    const int row0 = blockIdx.x * BM;
    const int col0 = blockIdx.y * 64;        // in [0, 2*COUT)
    const int l15 = lane & 15;
    const int kg = lane >> 4;                // 0..3
    const int srow = t >> 2;                 // staging: 4 thr/row
    const int sseg = (t & 3) * 8;            // 8 bf16 = 16B
    f32x4 acc[2][2] = {};

    for (int k0 = 0; k0 < K; k0 += 32) {
        __syncthreads();
        {
            uint4 a = {0, 0, 0, 0};
            const int gr = row0 + srow;
            if (gr < Mrows) a = *(const uint4*)&xb[(size_t)gr * K + k0 + sseg];
            *(uint4*)&As[srow][sseg] = a;
        }
        __syncthreads();
        bf16x8 af[2], bfr[2];
#pragma unroll
        for (int fi = 0; fi < 2; fi++)
            af[fi] = *(const bf16x8*)&As[wr * 32 + fi * 16 + l15][kg * 8];
#pragma unroll
        for (int fj = 0; fj < 2; fj++) {
            const int c = col0 + wc * 32 + fj * 16 + l15;
            bfr[fj] = *(const bf16x8*)&Wt[(size_t)c * K + k0 + kg * 8];
        }
#pragma unroll
        for (int fi = 0; fi < 2; fi++)
#pragma unroll
            for (int fj = 0; fj < 2; fj++)
                acc[fi][fj] = __builtin_amdgcn_mfma_f32_16x16x32_bf16(
                    af[fi], bfr[fj], acc[fi][fj], 0, 0, 0);
    }
    // D layout (m89-verified): col = lane&15, row = (lane>>4)*4 + reg
    const bool isU = col0 < COUT;
#pragma unroll
    for (int fi = 0; fi < 2; fi++) {
#pragma unroll
        for (int fj = 0; fj < 2; fj++) {
            const int c = col0 + wc * 32 + fj * 16 + l15;
#pragma unroll
            for (int r = 0; r < 4; r++) {
                const int row = row0 + wr * 32 + fi * 16 + kg * 4 + r;
                if (row < Mrows) {
                    if (isU) Ub[(size_t)row * COUT + c] = f2bf(acc[fi][fj][r] + bias[c]);
                    else     Vb[(size_t)row * COUT + (c - COUT)] = f2bf(acc[fi][fj][r]);
                }
            }
        }
    }
}

// ---------------- dense edge agg: out_bf16[i] = mean_j relu(u_i + v_j) ------------
// bf16 U + V, 8 ch/lane, LDS-staged csr with block-uniform fast path.

template <int C, int CAP>
__global__ __launch_bounds__(256) void k_edge_agg(const ushort* __restrict__ Ub,
                                                  const ushort* __restrict__ Vb,
                                                  const int* __restrict__ offsets,
                                                  const int* __restrict__ csr,
                                                  int nbase, int nnodes,
                                                  ushort* __restrict__ outb) {
    constexpr int TPN = C / 8;          // lanes per node (8 bf16 ch each)
    constexpr int NPB = 256 / TPN;      // nodes per block
    __shared__ int soff[NPB + 1];
    __shared__ int scsr[CAP];
    const int t = threadIdx.x;
    const int n0 = blockIdx.x * NPB;
    if (t <= NPB) {
        const int idx = min(n0 + t, nnodes);
        soff[t] = max(0, min(offsets[nbase + idx], ET));
    }
    __syncthreads();
    const int base = soff[0];
    const int span = soff[NPB] - base;
    const int tot = min(span, CAP);
    for (int k = t; k < tot; k += 256) scsr[k] = csr[base + k];
    __syncthreads();
    const bool allin = span <= CAP;     // block-uniform

    const int sub = t / TPN;
    const int c8 = (t % TPN) * 8;
    const int i = n0 + sub;
    if (i >= nnodes) return;
    const int beg = soff[sub];
    const int end = max(soff[sub + 1], beg);
    float u[8], acc[8] = {};
    unpack_bf8(u, *(const uint4*)&Ub[(size_t)i * C + c8]);
    if (allin) {
        int o = beg - base;
        const int oend = end - base;
        for (; o + 8 <= oend; o += 8) {
            int jj[8];
#pragma unroll
            for (int q = 0; q < 8; q++) jj[q] = scsr[o + q];
            uint4 w[8];
#pragma unroll
            for (int q = 0; q < 8; q++) w[q] = *(const uint4*)&Vb[(size_t)jj[q] * C + c8];
#pragma unroll
            for (int q = 0; q < 8; q++) acc_bf8(acc, u, w[q]);
        }
        for (; o < oend; ++o)
            acc_bf8(acc, u, *(const uint4*)&Vb[(size_t)scsr[o] * C + c8]);
    } else {
        for (int e = beg; e < end; ++e)
            acc_bf8(acc, u, *(const uint4*)&Vb[(size_t)csr[e] * C + c8]);
    }
    const int dg = end - beg;
    const float inv = 1.f / (float)(dg > 0 ? dg : 1);
    uint4 o;
    o.x = pack2(acc[0] * inv, acc[1] * inv);
    o.y = pack2(acc[2] * inv, acc[3] * inv);
    o.z = pack2(acc[4] * inv, acc[5] * inv);
    o.w = pack2(acc[6] * inv, acc[7] * inv);
    *(uint4*)&outb[(size_t)i * C + c8] = o;
}

// ---------------- fused dual agg (Res_up output), bf16 U/V, fast path -------------
// Partitioned CSR: [beg, beg+vc) valid gathers; remaining cnt edges -> cnt*relu(u).

template <int C, int CAP>
__global__ __launch_bounds__(256) void k_edge_agg_fused(const ushort* __restrict__ U2b,
                                                        const ushort* __restrict__ V2b,
                                                        const ushort* __restrict__ Uskb,
                                                        const ushort* __restrict__ Vskb,
                                                        const float* __restrict__ b2,
                                                        const float* __restrict__ bsk,
                                                        const int* __restrict__ offsets,
                                                        const int* __restrict__ vcnt,
                                                        const int* __restrict__ csr,
                                                        int nbase, int nnodes, int nnz,
                                                        ushort* __restrict__ outb) {
    constexpr int COUTc = C / Bn;
    constexpr int TPN = C / 8;
    constexpr int NPB = 256 / TPN;
    __shared__ int soff[NPB + 1];
    __shared__ int svc[NPB];
    __shared__ int scsr[CAP];
    const int t = threadIdx.x;
    const int n0 = blockIdx.x * NPB;
    if (t <= NPB) {
        const int idx = min(n0 + t, nnodes);
        soff[t] = max(0, min(offsets[nbase + idx], ET));
    }
    if (t < NPB) svc[t] = (n0 + t < nnodes) ? vcnt[nbase + n0 + t] : 0;
    __syncthreads();
    const int base = soff[0];
    const int span = soff[NPB] - base;
    const int tot = min(span, CAP);
    for (int k = t; k < tot; k += 256) scsr[k] = csr[base + k];
    __syncthreads();
    const bool allin = span <= CAP;     // block-uniform

    const int sub = t / TPN;
    const int c8 = (t % TPN) * 8;
    const int i = n0 + sub;
    if (i >= nnodes) return;
    const int beg = soff[sub];
    const int end = max(soff[sub + 1], beg);
    const int dg = end - beg;
    const int vc = max(0, min(svc[sub], dg));
    const int cb = c8 & (COUTc - 1);
    float u2[8], usk[8];
    if (i < nnz) {
        unpack_bf8(u2,  *(const uint4*)&U2b[(size_t)i * C + c8]);
        unpack_bf8(usk, *(const uint4*)&Uskb[(size_t)i * C + c8]);
    } else {
        *(float4*)&u2[0]  = *(const float4*)&b2[cb];
        *(float4*)&u2[4]  = *(const float4*)&b2[cb + 4];
        *(float4*)&usk[0] = *(const float4*)&bsk[cb];
        *(float4*)&usk[4] = *(const float4*)&bsk[cb + 4];
    }
    float a2[8] = {}, ask[8] = {};
    if (allin) {
        int o = beg - base;
        const int oend = o + vc;
        for (; o + 4 <= oend; o += 4) {
            int jj[4];
#pragma unroll
            for (int q = 0; q < 4; q++) jj[q] = scsr[o + q];
            uint4 pv[4], qv[4];
#pragma unroll
            for (int q = 0; q < 4; q++) pv[q] = *(const uint4*)&V2b[(size_t)jj[q] * C + c8];
#pragma unroll
            for (int q = 0; q < 4; q++) qv[q] = *(const uint4*)&Vskb[(size_t)jj[q] * C + c8];
#pragma unroll
            for (int q = 0; q < 4; q++) { acc_bf8(a2, u2, pv[q]); acc_bf8(ask, usk, qv[q]); }
        }
        for (; o < oend; ++o) {
            const int j = scsr[o];
            acc_bf8(a2, u2, *(const uint4*)&V2b[(size_t)j * C + c8]);
            acc_bf8(ask, usk, *(const uint4*)&Vskb[(size_t)j * C + c8]);
        }
    } else {
        for (int e = beg; e < beg + vc; ++e) {
            const int j = csr[e];
            acc_bf8(a2, u2, *(const uint4*)&V2b[(size_t)j * C + c8]);
            acc_bf8(ask, usk, *(const uint4*)&Vskb[(size_t)j * C + c8]);
        }
    }
    const int cnt = dg - vc;                  // edges with j >= nnz: v = 0
    if (cnt > 0) {
        const float fc = (float)cnt;
#pragma unroll
        for (int k = 0; k < 8; k++) {
            a2[k]  += fc * fmaxf(u2[k], 0.f);
            ask[k] += fc * fmaxf(usk[k], 0.f);
        }
    }
    const float inv = 1.f / (float)(dg > 0 ? dg : 1);
    float ov[8];
#pragma unroll
    for (int k = 0; k < 8; k++) ov[k] = lrelu((a2[k] + ask[k]) * inv);
    uint4 o;
    o.x = pack2(ov[0], ov[1]); o.y = pack2(ov[2], ov[3]);
    o.z = pack2(ov[4], ov[5]); o.w = pack2(ov[6], ov[7]);
    *(uint4*)&outb[(size_t)i * C + c8] = o;
}

// ---------------- fused final agg + decoder MLP + LayerNorm(3) ----------------
// 16 nodes/block, 16 lanes/node, bf16 U/V, LDS-staged csr + fast path.

__global__ __launch_bounds__(256) void k_agg_dec(const ushort* __restrict__ Ub,
                                                 const ushort* __restrict__ Vb,
                                                 const int* __restrict__ offsets,
                                                 const int* __restrict__ csr,
                                                 const float* __restrict__ Wd1,
                                                 const float* __restrict__ bd1,
                                                 const float* __restrict__ Wd2,
                                                 const float* __restrict__ bd2,
                                                 const float* __restrict__ gamma,
                                                 const float* __restrict__ beta,
                                                 float* __restrict__ out) {
    constexpr int C = 128;
    constexpr int CAP = 768;
    __shared__ float w1[2048];          // Wd1 [64,32]
    __shared__ float w2[96];            // Wd2 [32,3]
    __shared__ float sb1[32], sb2[3], sg[3], sbt[3];
    __shared__ float xs[32 * 66];       // 32 (n,b) rows of 64, stride 66
    __shared__ float hs[32][33];        // h1 per row
    __shared__ int soff[17];
    __shared__ int scsr[CAP];
    const int t = threadIdx.x;
    for (int i = t; i < 2048; i += 256) w1[i] = Wd1[i];
    if (t < 96) w2[t] = Wd2[t];
    if (t < 32) sb1[t] = bd1[t];
    if (t < 3) { sb2[t] = bd2[t]; sg[t] = gamma[t]; sbt[t] = beta[t]; }

    const int n0 = blockIdx.x * 16;
    if (t <= 16) {
        const int idx = min(n0 + t, N0n);
        soff[t] = max(0, min(offsets[idx], ET));
    }
    __syncthreads();
    const int base = soff[0];
    const int span = soff[16] - base;
    const int tot = min(span, CAP);
    for (int k = t; k < tot; k += 256) scsr[k] = csr[base + k];
    __syncthreads();
    const bool allin = span <= CAP;     // block-uniform

    // --- agg phase: 16 nodes/block, 16 thr/node, 8 bf16 ch/lane ---
    const int sub = t >> 4;
    const int c8 = (t & 15) * 8;        // channel = b*64 + k
    const int i0 = n0 + sub;
    float r[8] = {};
    if (i0 < N0n) {
        const int beg = soff[sub];
        const int end = max(soff[sub + 1], beg);
        float u[8], acc[8] = {};
        unpack_bf8(u, *(const uint4*)&Ub[(size_t)i0 * C + c8]);
        if (allin) {
            int o = beg - base;
            const int oend = end - base;
            for (; o + 8 <= oend; o += 8) {
                int jj[8];
#pragma unroll
                for (int q = 0; q < 8; q++) jj[q] = scsr[o + q];
                uint4 w[8];
#pragma unroll
                for (int q = 0; q < 8; q++) w[q] = *(const uint4*)&Vb[(size_t)jj[q] * C + c8];
#pragma unroll
                for (int q = 0; q < 8; q++) acc_bf8(acc, u, w[q]);
            }
            for (; o < oend; ++o)
                acc_bf8(acc, u, *(const uint4*)&Vb[(size_t)scsr[o] * C + c8]);
        } else {
            for (int e = beg; e < end; ++e)
                acc_bf8(acc, u, *(const uint4*)&Vb[(size_t)csr[e] * C + c8]);
        }
        const int dg = end - beg;
        const float inv = 1.f / (float)(dg > 0 ? dg : 1);
#pragma unroll
        for (int k = 0; k < 8; k++) r[k] = acc[k] * inv;
    }
    // stage into LDS: row = sub*2 + b, col = k (8 entries per lane)
    {
        const int rrow = sub * 2 + (c8 >> 6);
        const int rk = c8 & 63;
        float* xp = &xs[rrow * 66 + rk];
#pragma unroll
        for (int k = 0; k < 8; k++) xp[k] = r[k];
    }
    __syncthreads();

    // --- decoder: 32 rows x 8 threads; thread computes h1[l8+8m], m=0..3 ---
    const int drow = t >> 3;
    const int l8 = t & 7;
    float h1[4] = {sb1[l8], sb1[l8 + 8], sb1[l8 + 16], sb1[l8 + 24]};
    const float* xrow = &xs[drow * 66];
#pragma unroll 8
    for (int k = 0; k < 64; k++) {
        const float xk = xrow[k];
        h1[0] += xk * w1[k * 32 + l8];
        h1[1] += xk * w1[k * 32 + l8 + 8];
        h1[2] += xk * w1[k * 32 + l8 + 16];
        h1[3] += xk * w1[k * 32 + l8 + 24];
    }
    hs[drow][l8]      = lrelu(h1[0]);
    hs[drow][l8 + 8]  = lrelu(h1[1]);
    hs[drow][l8 + 16] = lrelu(h1[2]);
    hs[drow][l8 + 24] = lrelu(h1[3]);
    __syncthreads();

    // --- h2 + LN: one thread per row ---
    if (t < 32) {
        const int node = t >> 1, b = t & 1;
        const int n = n0 + node;
        if (n < N0n) {
            float h2[3];
#pragma unroll
            for (int j = 0; j < 3; j++) {
                float s = sb2[j];
#pragma unroll
                for (int c = 0; c < 32; c++) s += hs[t][c] * w2[c * 3 + j];
                h2[j] = s;
            }
            const float mu = (h2[0] + h2[1] + h2[2]) * (1.f / 3.f);
            const float d0 = h2[0] - mu, d1 = h2[1] - mu, d2 = h2[2] - mu;
            const float var = (d0 * d0 + d1 * d1 + d2 * d2) * (1.f / 3.f);
            const float inv = rsqrtf(var + 1e-5f);
            const size_t ob = (size_t)b * N0n * 3 + (size_t)n * 3;
            out[ob + 0] = d0 * inv * sg[0] + sbt[0];
            out[ob + 1] = d1 * inv * sg[1] + sbt[1];
            out[ob + 2] = d2 * inv * sg[2] + sbt[2];
        }
    }
}

// ---------------- launch ----------------

extern "C" void kernel_launch(void* const* d_in, const int* in_sizes, int n_in,
                              void* d_out, int out_size, void* d_ws, size_t ws_size,
                              hipStream_t stream) {
    (void)in_sizes; (void)n_in; (void)out_size; (void)ws_size;
    const float* z   = (const float*)d_in[0];
    const int* g0    = (const int*)d_in[1];
    const int* g1    = (const int*)d_in[2];
    const int* g2    = (const int*)d_in[3];
    const float* W_up1 = (const float*)d_in[6];
    const float* b_up1 = (const float*)d_in[7];
    const float* W_up2 = (const float*)d_in[8];
    const float* b_up2 = (const float*)d_in[9];
    const float* Wb    = (const float*)d_in[10];
    const float* bb    = (const float*)d_in[11];
    const float* l0_W1 = (const float*)d_in[12];
    const float* l0_b1 = (const float*)d_in[13];
    const float* l0_W2 = (const float*)d_in[14];
    const float* l0_b2 = (const float*)d_in[15];
    const float* l0_Wsk = (const float*)d_in[16];
    const float* l0_bsk = (const float*)d_in[17];
    const float* l1_W1 = (const float*)d_in[18];
    const float* l1_b1 = (const float*)d_in[19];
    const float* l1_W2 = (const float*)d_in[20];
    const float* l1_b2 = (const float*)d_in[21];
    const float* l1_Wsk = (const float*)d_in[22];
    const float* l1_bsk = (const float*)d_in[23];
    const float* Wf    = (const float*)d_in[24];
    const float* bf_   = (const float*)d_in[25];
    const float* Wd1   = (const float*)d_in[26];
    const float* bd1   = (const float*)d_in[27];
    const float* Wd2   = (const float*)d_in[28];
    const float* bd2   = (const float*)d_in[29];
    const float* gamma = (const float*)d_in[30];
    const float* beta  = (const float*)d_in[31];

    char* p = (char*)d_ws;
    auto alloc = [&](size_t bytes) -> char* {
        char* r = p; p += (bytes + 255) & ~(size_t)255; return r;
    };
    int* offsets  = (int*)alloc((size_t)(NT + 1) * 4);
    int* partials = (int*)alloc((size_t)NCHUNK * 4);
    int* degcur   = (int*)alloc((size_t)3 * NT * 4);
    int* deg = degcur; int* cursor = degcur + NT; int* bcur = degcur + 2 * NT;
    int* csr = (int*)alloc((size_t)ET * 4);

    // bf16 weight buffers (Wt[2*COUT][K]) for the 8 MFMA GEMMs
    ushort* Wt0 = (ushort*)alloc(65536 * 2);   // conv1  K=128 C=256
    ushort* Wt1 = (ushort*)alloc(32768 * 2);   // l0_W1  K=256 C=64
    ushort* Wt2 = (ushort*)alloc(16384 * 2);   // l0_W2  K=64  C=128
    ushort* Wt3 = (ushort*)alloc(65536 * 2);   // skip0  K=256 C=128
    ushort* Wt4 = (ushort*)alloc(16384 * 2);   // l1_W1  K=128 C=64
    ushort* Wt5 = (ushort*)alloc(8192 * 2);    // l1_W2  K=64  C=64
    ushort* Wt6 = (ushort*)alloc(16384 * 2);   // skip1  K=128 C=64
    ushort* Wt7 = (ushort*)alloc(8192 * 2);    // final  K=64  C=64

    // pooled slabs: A,B,C = 12.8M floats (51.2 MB) each, D = 3.2M floats.
    // All activations/U/V are bf16 now (half-occupied granules) — offsets kept.
    constexpr size_t SLOT = (size_t)N0n * Bn * 64;   // 12.8M floats
    constexpr size_t M1 = 1600000;                    // 1.6M-float granule
    float* A = (float*)alloc(SLOT * 4);
    float* B = (float*)alloc(SLOT * 4);
    float* C = (float*)alloc(SLOT * 4);
    float* D = (float*)alloc((size_t)N1n * Bn * 64 * 4);

    // --- CSR build + weight prep ---
    hipMemsetAsync(degcur, 0, (size_t)3 * NT * 4, stream);
    k_wprep<<<256, 256, 0, stream>>>(Wb, Wt0, l0_W1, Wt1, l0_W2, Wt2, l0_Wsk, Wt3,
                                     l1_W1, Wt4, l1_W2, Wt5, l1_Wsk, Wt6, Wf, Wt7);
    k_deg_count<<<(QT + 255) / 256, 256, 0, stream>>>(g0, g1, g2, deg);
    k_scan1<<<NCHUNK, 256, 0, stream>>>(deg, offsets, partials);
    k_scan3<<<(NT + 255) / 256, 256, 0, stream>>>(partials, offsets);
    k_csr_fill<<<(QT + 255) / 256, 256, 0, stream>>>(g0, g1, g2, offsets, cursor, bcur, csr);

    const int nb2 = N0n + N1n;   // g2 node base in offsets
    const int nb1 = N0n;         // g1 node base

    // --- latent -> x0 bf16 [12500,128] @ A[0,M1) ---
    ushort* x0b = (ushort*)A;
    k_latent<<<(N2n + 7) / 8, 256, 0, stream>>>(z, W_up1, b_up1, W_up2, b_up2, x0b);

    // --- conv1 (g2, 128->256): Ub@A[M1,..) Vb@A[3M1,..) -> xc1 bf16 @ A[5M1,..) ---
    ushort* xc1b = (ushort*)(A + 5 * M1);
    k_gemm_mfma<128, 256><<<dim3(196, 8), 256, 0, stream>>>(x0b, Wt0, bb,
                                                            (ushort*)(A + M1), (ushort*)(A + 3 * M1),
                                                            N2n * Bn);
    k_edge_agg<512, 256><<<(N2n + 3) / 4, 256, 0, stream>>>((const ushort*)(A + M1),
                                                            (const ushort*)(A + 3 * M1),
                                                            offsets, csr, nb2, N2n, xc1b);

    // --- l0_W1 (g2, 256->64): -> t1 bf16 @ A[0,M1) (x0 dead) ---
    ushort* t1b = (ushort*)A;
    k_gemm_mfma<256, 64><<<dim3(196, 2), 256, 0, stream>>>(xc1b, Wt1, l0_b1,
                                                           (ushort*)(A + 7 * M1),
                                                           (ushort*)(A + 7 * M1 + 800000),
                                                           N2n * Bn);
    k_edge_agg<128, 768><<<(N2n + 15) / 16, 256, 0, stream>>>((const ushort*)(A + 7 * M1),
                                                              (const ushort*)(A + 7 * M1 + 800000),
                                                              offsets, csr, nb2, N2n, t1b);

    // --- l0_W2 (64->128): U2b@B[0,M1) V2b@B[M1,..) ---
    k_gemm_mfma<64, 128><<<dim3(196, 4), 256, 0, stream>>>(t1b, Wt2, l0_b2,
                                                           (ushort*)B, (ushort*)(B + M1), N2n * Bn);
    // --- skip0 (256->128): Uskb@B[2M1,..) Vskb@B[3M1,..) ---
    k_gemm_mfma<256, 128><<<dim3(196, 4), 256, 0, stream>>>(xc1b, Wt3, l0_bsk,
                                                            (ushort*)(B + 2 * M1), (ushort*)(B + 3 * M1),
                                                            N2n * Bn);
    // --- fused layer0 agg (g1, C=256, nnz=N2n): -> x1 bf16 @ B[4M1,..) ---
    ushort* x1b = (ushort*)(B + 4 * M1);
    k_edge_agg_fused<256, 512><<<(N1n + 7) / 8, 256, 0, stream>>>((const ushort*)B,
                                                                  (const ushort*)(B + M1),
                                                                  (const ushort*)(B + 2 * M1),
                                                                  (const ushort*)(B + 3 * M1),
                                                                  l0_b2, l0_bsk, offsets, cursor, csr,
                                                                  nb1, N1n, N2n, x1b);

    // --- l1_W1 (g1, 128->64): Ub@A[0,..) Vb@A[2M1,..) -> t2 bf16 @ D ---
    ushort* t2b = (ushort*)D;
    k_gemm_mfma<128, 64><<<dim3(782, 2), 256, 0, stream>>>(x1b, Wt4, l1_b1,
                                                           (ushort*)A, (ushort*)(A + 2 * M1), N1n * Bn);
    k_edge_agg<128, 768><<<(N1n + 15) / 16, 256, 0, stream>>>((const ushort*)A,
                                                              (const ushort*)(A + 2 * M1),
                                                              offsets, csr, nb1, N1n, t2b);

    // --- l1_W2 (64->64): U2b@A[0,..) V2b@A[2M1,..) ---
    k_gemm_mfma<64, 64><<<dim3(782, 2), 256, 0, stream>>>(t2b, Wt5, l1_b2,
                                                          (ushort*)A, (ushort*)(A + 2 * M1), N1n * Bn);
    // --- skip1 (128->64): Uskb@A[4M1,..) Vskb@A[6M1,..) ---
    k_gemm_mfma<128, 64><<<dim3(782, 2), 256, 0, stream>>>(x1b, Wt6, l1_bsk,
                                                           (ushort*)(A + 4 * M1), (ushort*)(A + 6 * M1),
                                                           N1n * Bn);
    // --- fused layer1 agg (g0, C=128, nnz=N1n): -> x2 bf16 @ C ---
    ushort* x2b = (ushort*)C;
    k_edge_agg_fused<128, 768><<<(N0n + 15) / 16, 256, 0, stream>>>((const ushort*)A,
                                                                    (const ushort*)(A + 2 * M1),
                                                                    (const ushort*)(A + 4 * M1),
                                                                    (const ushort*)(A + 6 * M1),
                                                                    l1_b2, l1_bsk, offsets, cursor, csr,
                                                                    0, N0n, N1n, x2b);

    // --- final conv (g0, 64->64): x2 -> Ufb bf16 @ A, Vfb bf16 @ B ---
    k_gemm_mfma<64, 64><<<dim3(3125, 2), 256, 0, stream>>>(x2b, Wt7, bf_,
                                                           (ushort*)A, (ushort*)B, N0n * Bn);
    // --- fused final agg + decoder + LN -> d_out ---
    k_agg_dec<<<(N0n + 15) / 16, 256, 0, stream>>>((const ushort*)A, (const ushort*)B, offsets, csr,
                                                   Wd1, bd1, Wd2, bd2, gamma, beta,
                                                   (float*)d_out);
}

// Round 10
// 494.554 us; speedup vs baseline: 1.0475x; 1.0475x over previous
//
#include <hip/hip_runtime.h>
#include <hip/hip_bf16.h>
#include <cstdint>

#define DEV_INLINE __device__ __forceinline__

// problem constants
constexpr int N0n = 100000, N1n = 25000, N2n = 6250;
constexpr int E0n = 800000, E1n = 200000, E2n = 50000;
constexpr int NT  = N0n + N1n + N2n;     // 131250 concatenated node space
constexpr int ET  = E0n + E1n + E2n;     // 1050000 concatenated edge space
constexpr int Bn  = 2;

DEV_INLINE float lrelu(float x) { return x > 0.f ? x : 0.01f * x; }

// r10: r9's 8-wide gather batch pushed k_agg_dec over the 64-VGPR occupancy
// cliff (44->64 VGPR, occ 44->36%, 69->85us). Depth>=4 was proven useless in
// r1-r3, so batches revert to 4-wide; bf16-U + LDS-csr fast path + vector CSR
// build (the r9 wins) are kept.
DEV_INLINE ushort f2bf(float f) {
    uint32_t u = __builtin_bit_cast(uint32_t, f);
    u += 0x7FFFu + ((u >> 16) & 1u);       // round-to-nearest-even
    return (ushort)(u >> 16);
}
DEV_INLINE float bflo(uint32_t w) { return __builtin_bit_cast(float, w << 16); }
DEV_INLINE float bfhi(uint32_t w) { return __builtin_bit_cast(float, w & 0xFFFF0000u); }
DEV_INLINE uint32_t pack2(float a, float b) {
    return (uint32_t)f2bf(a) | ((uint32_t)f2bf(b) << 16);
}
DEV_INLINE void unpack_bf8(float* u, const uint4 w) {
    u[0] = bflo(w.x); u[1] = bfhi(w.x);
    u[2] = bflo(w.y); u[3] = bfhi(w.y);
    u[4] = bflo(w.z); u[5] = bfhi(w.z);
    u[6] = bflo(w.w); u[7] = bfhi(w.w);
}

// acc[k] += relu(u[k] + v[k]) for 8 bf16 channels packed in a uint4
DEV_INLINE void acc_bf8(float* acc, const float* u, const uint4 w) {
    acc[0] += fmaxf(u[0] + bflo(w.x), 0.f);
    acc[1] += fmaxf(u[1] + bfhi(w.x), 0.f);
    acc[2] += fmaxf(u[2] + bflo(w.y), 0.f);
    acc[3] += fmaxf(u[3] + bfhi(w.y), 0.f);
    acc[4] += fmaxf(u[4] + bflo(w.z), 0.f);
    acc[5] += fmaxf(u[5] + bfhi(w.z), 0.f);
    acc[6] += fmaxf(u[6] + bflo(w.w), 0.f);
    acc[7] += fmaxf(u[7] + bfhi(w.w), 0.f);
}

typedef short bf16x8 __attribute__((ext_vector_type(8)));
typedef float f32x4 __attribute__((ext_vector_type(4)));

// ---------------- CSR build (3 graphs concatenated), 4 edges/thread ----------------

constexpr int Q0 = E0n / 4, Q1 = E1n / 4, Q2 = E2n / 4;   // 200000 / 50000 / 12500
constexpr int QT = Q0 + Q1 + Q2;                           // 262500

__global__ __launch_bounds__(256) void k_deg_count(const int* __restrict__ g0,
                                                   const int* __restrict__ g1,
                                                   const int* __restrict__ g2,
                                                   int* __restrict__ deg) {
    const int q = blockIdx.x * 256 + threadIdx.x;
    int4 d; int mod_, nb_;
    if (q < Q0)            { d = *(const int4*)&g0[E0n + q * 4];            mod_ = N0n; nb_ = 0; }
    else if (q < Q0 + Q1)  { d = *(const int4*)&g1[E1n + (q - Q0) * 4];     mod_ = N1n; nb_ = N0n; }
    else if (q < QT)       { d = *(const int4*)&g2[E2n + (q - Q0 - Q1) * 4]; mod_ = N2n; nb_ = N0n + N1n; }
    else return;
    atomicAdd(&deg[nb_ + d.x % mod_], 1);
    atomicAdd(&deg[nb_ + d.y % mod_], 1);
    atomicAdd(&deg[nb_ + d.z % mod_], 1);
    atomicAdd(&deg[nb_ + d.w % mod_], 1);
}

constexpr int SCAN_CHUNK = 2048;
constexpr int NCHUNK = (NT + SCAN_CHUNK - 1) / SCAN_CHUNK;   // 65

__global__ __launch_bounds__(256) void k_scan1(const int* __restrict__ deg,
                                               int* __restrict__ out,
                                               int* __restrict__ partials) {
    __shared__ int sums[256];
    const int chunk = blockIdx.x, t = threadIdx.x;
    const int base = chunk * SCAN_CHUNK + t * 8;
    int v[8]; int s = 0;
#pragma unroll
    for (int i = 0; i < 8; i++) { int idx = base + i; v[i] = (idx < NT) ? deg[idx] : 0; s += v[i]; }
    int val = s;
    sums[t] = val; __syncthreads();
    for (int off = 1; off < 256; off <<= 1) {
        int y = (t >= off) ? sums[t - off] : 0;
        __syncthreads();
        val += y; sums[t] = val;
        __syncthreads();
    }
    const int excl = val - s;
    if (t == 255) partials[chunk] = val;
    int run = excl;
#pragma unroll
    for (int i = 0; i < 8; i++) { int idx = base + i; if (idx < NT) out[idx] = run; run += v[i]; }
}

// scan2 folded in: each block redundantly prefix-sums the 65 partials in LDS.
__global__ __launch_bounds__(256) void k_scan3(const int* __restrict__ partials,
                                               int* __restrict__ offsets) {
    __shared__ int s[NCHUNK];
    __shared__ int pre[NCHUNK + 1];
    const int t = threadIdx.x;
    if (t < NCHUNK) s[t] = partials[t];
    __syncthreads();
    if (t == 0) {
        int run = 0;
        for (int i = 0; i < NCHUNK; i++) { pre[i] = run; run += s[i]; }
        pre[NCHUNK] = run;
    }
    __syncthreads();
    const int idx = blockIdx.x * 256 + t;
    if (idx < NT) offsets[idx] += pre[idx / SCAN_CHUNK];
    if (idx == 0) offsets[NT] = pre[NCHUNK];   // == ET
}

// Partitioned fill (4 edges/thread): valid-unpool sources at segment front;
// cursor[] afterwards == per-node valid-source count (consumed by fused aggs).
__global__ __launch_bounds__(256) void k_csr_fill(const int* __restrict__ g0,
                                                  const int* __restrict__ g1,
                                                  const int* __restrict__ g2,
                                                  const int* __restrict__ offsets,
                                                  int* __restrict__ cursor,
                                                  int* __restrict__ bcur,
                                                  int* __restrict__ csr) {
    const int q = blockIdx.x * 256 + threadIdx.x;
    int4 sv, dv; int mod_, nb_, thr_;
    if (q < Q0) {
        sv = *(const int4*)&g0[q * 4]; dv = *(const int4*)&g0[E0n + q * 4];
        mod_ = N0n; nb_ = 0; thr_ = N1n;
    } else if (q < Q0 + Q1) {
        const int lq = q - Q0;
        sv = *(const int4*)&g1[lq * 4]; dv = *(const int4*)&g1[E1n + lq * 4];
        mod_ = N1n; nb_ = N0n; thr_ = N2n;
    } else if (q < QT) {
        const int lq = q - Q0 - Q1;
        sv = *(const int4*)&g2[lq * 4]; dv = *(const int4*)&g2[E2n + lq * 4];
        mod_ = N2n; nb_ = N0n + N1n; thr_ = N2n;   // src < N2n always -> front
    } else return;
    const int ss[4] = {sv.x, sv.y, sv.z, sv.w};
    const int dd[4] = {dv.x, dv.y, dv.z, dv.w};
#pragma unroll
    for (int i = 0; i < 4; i++) {
        const int src = ss[i] % mod_;
        const int gd = nb_ + dd[i] % mod_;
        const bool front = src < thr_;
        const int pos = front ? offsets[gd] + atomicAdd(&cursor[gd], 1)
                              : offsets[gd + 1] - 1 - atomicAdd(&bcur[gd], 1);
        if (pos >= 0 && pos < ET) csr[pos] = src;   // local src id
    }
}

// ---------------- weight prep: W[2K][COUT] fp32 -> Wt[2*COUT][K] bf16 ----------------

__global__ __launch_bounds__(256) void k_wprep(const float* W0, ushort* T0,
                                               const float* W1, ushort* T1,
                                               const float* W2, ushort* T2,
                                               const float* W3, ushort* T3,
                                               const float* W4, ushort* T4,
                                               const float* W5, ushort* T5,
                                               const float* W6, ushort* T6,
                                               const float* W7, ushort* T7) {
    constexpr int KS[8] = {128, 256, 64, 256, 128, 64, 128, 64};
    constexpr int CS[8] = {256, 64, 128, 128, 64, 64, 64, 64};
    const int set = blockIdx.x >> 5;          // 32 blocks / set
    const int blk = blockIdx.x & 31;
    const float* W; ushort* T;
    switch (set) {
        case 0: W = W0; T = T0; break;
        case 1: W = W1; T = T1; break;
        case 2: W = W2; T = T2; break;
        case 3: W = W3; T = T3; break;
        case 4: W = W4; T = T4; break;
        case 5: W = W5; T = T5; break;
        case 6: W = W6; T = T6; break;
        default: W = W7; T = T7; break;
    }
    const int K = KS[set], C = CS[set];
    const int tot = 2 * C * K;
    for (int idx = blk * 256 + threadIdx.x; idx < tot; idx += 32 * 256) {
        const int n = idx / K, k = idx % K;
        float v;
        if (n < C) v = W[(size_t)k * C + n] - W[(size_t)(K + k) * C + n];
        else       v = W[(size_t)(K + k) * C + (n - C)];
        T[idx] = f2bf(v);
    }
}

// ---------------- latent MLP: z -> x0 bf16 [N2*B, 128] ----------------

__global__ __launch_bounds__(256) void k_latent(const float* __restrict__ z,
                                                const float* __restrict__ W1,
                                                const float* __restrict__ b1,
                                                const float* __restrict__ W2,
                                                const float* __restrict__ b2,
                                                ushort* __restrict__ x0b) {
    __shared__ float col[64];
    const int t = threadIdx.x;
    const int b = t >> 7, l = t & 127;
    const float zv = z[b * 128 + l];
    float h1[64];
#pragma unroll
    for (int k = 0; k < 64; k++) h1[k] = lrelu(zv * W1[k] + b1[k]);
    for (int nn = 0; nn < 8; nn++) {
        const int n = blockIdx.x * 8 + nn;
        if (n >= N2n) break;                 // uniform across block
        if (t < 64) col[t] = W2[t * N2n + n];
        __syncthreads();
        float s = b2[n];
#pragma unroll
        for (int k = 0; k < 64; k++) s += h1[k] * col[k];
        x0b[((size_t)n * Bn + b) * 128 + l] = f2bf(s);
        __syncthreads();
    }
}

// ---------------- MFMA GEMM: D = x_bf @ [Wd | Wb]; U bf16 (+bias), V bf16 ----------
// 4 waves = 2x2 wave grid; wave = 32x32 via 2x2 mfma_f32_16x16x32_bf16 frags.

template <int K, int COUT>
__global__ __launch_bounds__(256) void k_gemm_mfma(const ushort* __restrict__ xb,
                                                   const ushort* __restrict__ Wt,
                                                   const float* __restrict__ bias,
                                                   ushort* __restrict__ Ub,
                                                   ushort* __restrict__ Vb,
                                                   int Mrows) {
    constexpr int BM = 64;
    __shared__ ushort As[64][40];
    const int t = threadIdx.x;
    const int lane = t & 63;
    const int wave = t >> 6;
    const int wr = wave >> 1, wc = wave & 1;
    const int row0 = blockIdx.x * BM;
    const int col0 = blockIdx.y * 64;        // in [0, 2*COUT)
    const int l15 = lane & 15;
    const int kg = lane >> 4;                // 0..3
    const int srow = t >> 2;                 // staging: 4 thr/row
    const int sseg = (t & 3) * 8;            // 8 bf16 = 16B
    f32x4 acc[2][2] = {};

    for (int k0 = 0; k0 < K; k0 += 32) {
        __syncthreads();
        {
            uint4 a = {0, 0, 0, 0};
            const int gr = row0 + srow;
            if (gr < Mrows) a = *(const uint4*)&xb[(size_t)gr * K + k0 + sseg];
            *(uint4*)&As[srow][sseg] = a;
        }
        __syncthreads();
        bf16x8 af[2], bfr[2];
#pragma unroll
        for (int fi = 0; fi < 2; fi++)
            af[fi] = *(const bf16x8*)&As[wr * 32 + fi * 16 + l15][kg * 8];
#pragma unroll
        for (int fj = 0; fj < 2; fj++) {
            const int c = col0 + wc * 32 + fj * 16 + l15;
            bfr[fj] = *(const bf16x8*)&Wt[(size_t)c * K + k0 + kg * 8];
        }
#pragma unroll
        for (int fi = 0; fi < 2; fi++)
#pragma unroll
            for (int fj = 0; fj < 2; fj++)
                acc[fi][fj] = __builtin_amdgcn_mfma_f32_16x16x32_bf16(
                    af[fi], bfr[fj], acc[fi][fj], 0, 0, 0);
    }
    // D layout (m89-verified): col = lane&15, row = (lane>>4)*4 + reg
    const bool isU = col0 < COUT;
#pragma unroll
    for (int fi = 0; fi < 2; fi++) {
#pragma unroll
        for (int fj = 0; fj < 2; fj++) {
            const int c = col0 + wc * 32 + fj * 16 + l15;
#pragma unroll
            for (int r = 0; r < 4; r++) {
                const int row = row0 + wr * 32 + fi * 16 + kg * 4 + r;
                if (row < Mrows) {
                    if (isU) Ub[(size_t)row * COUT + c] = f2bf(acc[fi][fj][r] + bias[c]);
                    else     Vb[(size_t)row * COUT + (c - COUT)] = f2bf(acc[fi][fj][r]);
                }
            }
        }
    }
}

// ---------------- dense edge agg: out_bf16[i] = mean_j relu(u_i + v_j) ------------
// bf16 U + V, 8 ch/lane, LDS-staged csr, block-uniform fast path, 4-wide batch.

template <int C, int CAP>
__global__ __launch_bounds__(256) void k_edge_agg(const ushort* __restrict__ Ub,
                                                  const ushort* __restrict__ Vb,
                                                  const int* __restrict__ offsets,
                                                  const int* __restrict__ csr,
                                                  int nbase, int nnodes,
                                                  ushort* __restrict__ outb) {
    constexpr int TPN = C / 8;          // lanes per node (8 bf16 ch each)
    constexpr int NPB = 256 / TPN;      // nodes per block
    __shared__ int soff[NPB + 1];
    __shared__ int scsr[CAP];
    const int t = threadIdx.x;
    const int n0 = blockIdx.x * NPB;
    if (t <= NPB) {
        const int idx = min(n0 + t, nnodes);
        soff[t] = max(0, min(offsets[nbase + idx], ET));
    }
    __syncthreads();
    const int base = soff[0];
    const int span = soff[NPB] - base;
    const int tot = min(span, CAP);
    for (int k = t; k < tot; k += 256) scsr[k] = csr[base + k];
    __syncthreads();
    const bool allin = span <= CAP;     // block-uniform

    const int sub = t / TPN;
    const int c8 = (t % TPN) * 8;
    const int i = n0 + sub;
    if (i >= nnodes) return;
    const int beg = soff[sub];
    const int end = max(soff[sub + 1], beg);
    float u[8], acc[8] = {};
    unpack_bf8(u, *(const uint4*)&Ub[(size_t)i * C + c8]);
    if (allin) {
        int o = beg - base;
        const int oend = end - base;
        for (; o + 4 <= oend; o += 4) {          // 4-wide: stays under VGPR cliff
            const int j0 = scsr[o], j1 = scsr[o + 1], j2 = scsr[o + 2], j3 = scsr[o + 3];
            const uint4 w0 = *(const uint4*)&Vb[(size_t)j0 * C + c8];
            const uint4 w1 = *(const uint4*)&Vb[(size_t)j1 * C + c8];
            const uint4 w2 = *(const uint4*)&Vb[(size_t)j2 * C + c8];
            const uint4 w3 = *(const uint4*)&Vb[(size_t)j3 * C + c8];
            acc_bf8(acc, u, w0); acc_bf8(acc, u, w1);
            acc_bf8(acc, u, w2); acc_bf8(acc, u, w3);
        }
        for (; o < oend; ++o)
            acc_bf8(acc, u, *(const uint4*)&Vb[(size_t)scsr[o] * C + c8]);
    } else {
        for (int e = beg; e < end; ++e)
            acc_bf8(acc, u, *(const uint4*)&Vb[(size_t)csr[e] * C + c8]);
    }
    const int dg = end - beg;
    const float inv = 1.f / (float)(dg > 0 ? dg : 1);
    uint4 o;
    o.x = pack2(acc[0] * inv, acc[1] * inv);
    o.y = pack2(acc[2] * inv, acc[3] * inv);
    o.z = pack2(acc[4] * inv, acc[5] * inv);
    o.w = pack2(acc[6] * inv, acc[7] * inv);
    *(uint4*)&outb[(size_t)i * C + c8] = o;
}

// ---------------- fused dual agg (Res_up output), bf16 U/V, fast path -------------
// Partitioned CSR: [beg, beg+vc) valid gathers; remaining cnt edges -> cnt*relu(u).

template <int C, int CAP>
__global__ __launch_bounds__(256) void k_edge_agg_fused(const ushort* __restrict__ U2b,
                                                        const ushort* __restrict__ V2b,
                                                        const ushort* __restrict__ Uskb,
                                                        const ushort* __restrict__ Vskb,
                                                        const float* __restrict__ b2,
                                                        const float* __restrict__ bsk,
                                                        const int* __restrict__ offsets,
                                                        const int* __restrict__ vcnt,
                                                        const int* __restrict__ csr,
                                                        int nbase, int nnodes, int nnz,
                                                        ushort* __restrict__ outb) {
    constexpr int COUTc = C / Bn;
    constexpr int TPN = C / 8;
    constexpr int NPB = 256 / TPN;
    __shared__ int soff[NPB + 1];
    __shared__ int svc[NPB];
    __shared__ int scsr[CAP];
    const int t = threadIdx.x;
    const int n0 = blockIdx.x * NPB;
    if (t <= NPB) {
        const int idx = min(n0 + t, nnodes);
        soff[t] = max(0, min(offsets[nbase + idx], ET));
    }
    if (t < NPB) svc[t] = (n0 + t < nnodes) ? vcnt[nbase + n0 + t] : 0;
    __syncthreads();
    const int base = soff[0];
    const int span = soff[NPB] - base;
    const int tot = min(span, CAP);
    for (int k = t; k < tot; k += 256) scsr[k] = csr[base + k];
    __syncthreads();
    const bool allin = span <= CAP;     // block-uniform

    const int sub = t / TPN;
    const int c8 = (t % TPN) * 8;
    const int i = n0 + sub;
    if (i >= nnodes) return;
    const int beg = soff[sub];
    const int end = max(soff[sub + 1], beg);
    const int dg = end - beg;
    const int vc = max(0, min(svc[sub], dg));
    const int cb = c8 & (COUTc - 1);
    float u2[8], usk[8];
    if (i < nnz) {
        unpack_bf8(u2,  *(const uint4*)&U2b[(size_t)i * C + c8]);
        unpack_bf8(usk, *(const uint4*)&Uskb[(size_t)i * C + c8]);
    } else {
        *(float4*)&u2[0]  = *(const float4*)&b2[cb];
        *(float4*)&u2[4]  = *(const float4*)&b2[cb + 4];
        *(float4*)&usk[0] = *(const float4*)&bsk[cb];
        *(float4*)&usk[4] = *(const float4*)&bsk[cb + 4];
    }
    float a2[8] = {}, ask[8] = {};
    if (allin) {
        int o = beg - base;
        const int oend = o + vc;
        for (; o + 2 <= oend; o += 2) {          // 2x2 tables = 4 gathers in flight
            const int j0 = scsr[o], j1 = scsr[o + 1];
            const uint4 p0 = *(const uint4*)&V2b[(size_t)j0 * C + c8];
            const uint4 p1 = *(const uint4*)&V2b[(size_t)j1 * C + c8];
            const uint4 q0 = *(const uint4*)&Vskb[(size_t)j0 * C + c8];
            const uint4 q1 = *(const uint4*)&Vskb[(size_t)j1 * C + c8];
            acc_bf8(a2, u2, p0); acc_bf8(a2, u2, p1);
            acc_bf8(ask, usk, q0); acc_bf8(ask, usk, q1);
        }
        for (; o < oend; ++o) {
            const int j = scsr[o];
            acc_bf8(a2, u2, *(const uint4*)&V2b[(size_t)j * C + c8]);
            acc_bf8(ask, usk, *(const uint4*)&Vskb[(size_t)j * C + c8]);
        }
    } else {
        for (int e = beg; e < beg + vc; ++e) {
            const int j = csr[e];
            acc_bf8(a2, u2, *(const uint4*)&V2b[(size_t)j * C + c8]);
            acc_bf8(ask, usk, *(const uint4*)&Vskb[(size_t)j * C + c8]);
        }
    }
    const int cnt = dg - vc;                  // edges with j >= nnz: v = 0
    if (cnt > 0) {
        const float fc = (float)cnt;
#pragma unroll
        for (int k = 0; k < 8; k++) {
            a2[k]  += fc * fmaxf(u2[k], 0.f);
            ask[k] += fc * fmaxf(usk[k], 0.f);
        }
    }
    const float inv = 1.f / (float)(dg > 0 ? dg : 1);
    float ov[8];
#pragma unroll
    for (int k = 0; k < 8; k++) ov[k] = lrelu((a2[k] + ask[k]) * inv);
    uint4 o;
    o.x = pack2(ov[0], ov[1]); o.y = pack2(ov[2], ov[3]);
    o.z = pack2(ov[4], ov[5]); o.w = pack2(ov[6], ov[7]);
    *(uint4*)&outb[(size_t)i * C + c8] = o;
}

// ---------------- fused final agg + decoder MLP + LayerNorm(3) ----------------
// 16 nodes/block, 16 lanes/node, bf16 U/V, LDS-csr fast path, 4-wide batch.

__global__ __launch_bounds__(256) void k_agg_dec(const ushort* __restrict__ Ub,
                                                 const ushort* __restrict__ Vb,
                                                 const int* __restrict__ offsets,
                                                 const int* __restrict__ csr,
                                                 const float* __restrict__ Wd1,
                                                 const float* __restrict__ bd1,
                                                 const float* __restrict__ Wd2,
                                                 const float* __restrict__ bd2,
                                                 const float* __restrict__ gamma,
                                                 const float* __restrict__ beta,
                                                 float* __restrict__ out) {
    constexpr int C = 128;
    constexpr int CAP = 768;
    __shared__ float w1[2048];          // Wd1 [64,32]
    __shared__ float w2[96];            // Wd2 [32,3]
    __shared__ float sb1[32], sb2[3], sg[3], sbt[3];
    __shared__ float xs[32 * 66];       // 32 (n,b) rows of 64, stride 66
    __shared__ float hs[32][33];        // h1 per row
    __shared__ int soff[17];
    __shared__ int scsr[CAP];
    const int t = threadIdx.x;
    for (int i = t; i < 2048; i += 256) w1[i] = Wd1[i];
    if (t < 96) w2[t] = Wd2[t];
    if (t < 32) sb1[t] = bd1[t];
    if (t < 3) { sb2[t] = bd2[t]; sg[t] = gamma[t]; sbt[t] = beta[t]; }

    const int n0 = blockIdx.x * 16;
    if (t <= 16) {
        const int idx = min(n0 + t, N0n);
        soff[t] = max(0, min(offsets[idx], ET));
    }
    __syncthreads();
    const int base = soff[0];
    const int span = soff[16] - base;
    const int tot = min(span, CAP);
    for (int k = t; k < tot; k += 256) scsr[k] = csr[base + k];
    __syncthreads();
    const bool allin = span <= CAP;     // block-uniform

    // --- agg phase: 16 nodes/block, 16 thr/node, 8 bf16 ch/lane ---
    const int sub = t >> 4;
    const int c8 = (t & 15) * 8;        // channel = b*64 + k
    const int i0 = n0 + sub;
    float r[8] = {};
    if (i0 < N0n) {
        const int beg = soff[sub];
        const int end = max(soff[sub + 1], beg);
        float u[8], acc[8] = {};
        unpack_bf8(u, *(const uint4*)&Ub[(size_t)i0 * C + c8]);
        if (allin) {
            int o = beg - base;
            const int oend = end - base;
            for (; o + 4 <= oend; o += 4) {      // 4-wide: stays under VGPR cliff
                const int j0 = scsr[o], j1 = scsr[o + 1], j2 = scsr[o + 2], j3 = scsr[o + 3];
                const uint4 w0 = *(const uint4*)&Vb[(size_t)j0 * C + c8];
                const uint4 w1v = *(const uint4*)&Vb[(size_t)j1 * C + c8];
                const uint4 w2v = *(const uint4*)&Vb[(size_t)j2 * C + c8];
                const uint4 w3 = *(const uint4*)&Vb[(size_t)j3 * C + c8];
                acc_bf8(acc, u, w0); acc_bf8(acc, u, w1v);
                acc_bf8(acc, u, w2v); acc_bf8(acc, u, w3);
            }
            for (; o < oend; ++o)
                acc_bf8(acc, u, *(const uint4*)&Vb[(size_t)scsr[o] * C + c8]);
        } else {
            for (int e = beg; e < end; ++e)
                acc_bf8(acc, u, *(const uint4*)&Vb[(size_t)csr[e] * C + c8]);
        }
        const int dg = end - beg;
        const float inv = 1.f / (float)(dg > 0 ? dg : 1);
#pragma unroll
        for (int k = 0; k < 8; k++) r[k] = acc[k] * inv;
    }
    // stage into LDS: row = sub*2 + b, col = k (8 entries per lane)
    {
        const int rrow = sub * 2 + (c8 >> 6);
        const int rk = c8 & 63;
        float* xp = &xs[rrow * 66 + rk];
#pragma unroll
        for (int k = 0; k < 8; k++) xp[k] = r[k];
    }
    __syncthreads();

    // --- decoder: 32 rows x 8 threads; thread computes h1[l8+8m], m=0..3 ---
    const int drow = t >> 3;
    const int l8 = t & 7;
    float h1[4] = {sb1[l8], sb1[l8 + 8], sb1[l8 + 16], sb1[l8 + 24]};
    const float* xrow = &xs[drow * 66];
#pragma unroll 8
    for (int k = 0; k < 64; k++) {
        const float xk = xrow[k];
        h1[0] += xk * w1[k * 32 + l8];
        h1[1] += xk * w1[k * 32 + l8 + 8];
        h1[2] += xk * w1[k * 32 + l8 + 16];
        h1[3] += xk * w1[k * 32 + l8 + 24];
    }
    hs[drow][l8]      = lrelu(h1[0]);
    hs[drow][l8 + 8]  = lrelu(h1[1]);
    hs[drow][l8 + 16] = lrelu(h1[2]);
    hs[drow][l8 + 24] = lrelu(h1[3]);
    __syncthreads();

    // --- h2 + LN: one thread per row ---
    if (t < 32) {
        const int node = t >> 1, b = t & 1;
        const int n = n0 + node;
        if (n < N0n) {
            float h2[3];
#pragma unroll
            for (int j = 0; j < 3; j++) {
                float s = sb2[j];
#pragma unroll
                for (int c = 0; c < 32; c++) s += hs[t][c] * w2[c * 3 + j];
                h2[j] = s;
            }
            const float mu = (h2[0] + h2[1] + h2[2]) * (1.f / 3.f);
            const float d0 = h2[0] - mu, d1 = h2[1] - mu, d2 = h2[2] - mu;
            const float var = (d0 * d0 + d1 * d1 + d2 * d2) * (1.f / 3.f);
            const float inv = rsqrtf(var + 1e-5f);
            const size_t ob = (size_t)b * N0n * 3 + (size_t)n * 3;
            out[ob + 0] = d0 * inv * sg[0] + sbt[0];
            out[ob + 1] = d1 * inv * sg[1] + sbt[1];
            out[ob + 2] = d2 * inv * sg[2] + sbt[2];
        }
    }
}

// ---------------- launch ----------------

extern "C" void kernel_launch(void* const* d_in, const int* in_sizes, int n_in,
                              void* d_out, int out_size, void* d_ws, size_t ws_size,
                              hipStream_t stream) {
    (void)in_sizes; (void)n_in; (void)out_size; (void)ws_size;
    const float* z   = (const float*)d_in[0];
    const int* g0    = (const int*)d_in[1];
    const int* g1    = (const int*)d_in[2];
    const int* g2    = (const int*)d_in[3];
    const float* W_up1 = (const float*)d_in[6];
    const float* b_up1 = (const float*)d_in[7];
    const float* W_up2 = (const float*)d_in[8];
    const float* b_up2 = (const float*)d_in[9];
    const float* Wb    = (const float*)d_in[10];
    const float* bb    = (const float*)d_in[11];
    const float* l0_W1 = (const float*)d_in[12];
    const float* l0_b1 = (const float*)d_in[13];
    const float* l0_W2 = (const float*)d_in[14];
    const float* l0_b2 = (const float*)d_in[15];
    const float* l0_Wsk = (const float*)d_in[16];
    const float* l0_bsk = (const float*)d_in[17];
    const float* l1_W1 = (const float*)d_in[18];
    const float* l1_b1 = (const float*)d_in[19];
    const float* l1_W2 = (const float*)d_in[20];
    const float* l1_b2 = (const float*)d_in[21];
    const float* l1_Wsk = (const float*)d_in[22];
    const float* l1_bsk = (const float*)d_in[23];
    const float* Wf    = (const float*)d_in[24];
    const float* bf_   = (const float*)d_in[25];
    const float* Wd1   = (const float*)d_in[26];
    const float* bd1   = (const float*)d_in[27];
    const float* Wd2   = (const float*)d_in[28];
    const float* bd2   = (const float*)d_in[29];
    const float* gamma = (const float*)d_in[30];
    const float* beta  = (const float*)d_in[31];

    char* p = (char*)d_ws;
    auto alloc = [&](size_t bytes) -> char* {
        char* r = p; p += (bytes + 255) & ~(size_t)255; return r;
    };
    int* offsets  = (int*)alloc((size_t)(NT + 1) * 4);
    int* partials = (int*)alloc((size_t)NCHUNK * 4);
    int* degcur   = (int*)alloc((size_t)3 * NT * 4);
    int* deg = degcur; int* cursor = degcur + NT; int* bcur = degcur + 2 * NT;
    int* csr = (int*)alloc((size_t)ET * 4);

    // bf16 weight buffers (Wt[2*COUT][K]) for the 8 MFMA GEMMs
    ushort* Wt0 = (ushort*)alloc(65536 * 2);   // conv1  K=128 C=256
    ushort* Wt1 = (ushort*)alloc(32768 * 2);   // l0_W1  K=256 C=64
    ushort* Wt2 = (ushort*)alloc(16384 * 2);   // l0_W2  K=64  C=128
    ushort* Wt3 = (ushort*)alloc(65536 * 2);   // skip0  K=256 C=128
    ushort* Wt4 = (ushort*)alloc(16384 * 2);   // l1_W1  K=128 C=64
    ushort* Wt5 = (ushort*)alloc(8192 * 2);    // l1_W2  K=64  C=64
    ushort* Wt6 = (ushort*)alloc(16384 * 2);   // skip1  K=128 C=64
    ushort* Wt7 = (ushort*)alloc(8192 * 2);    // final  K=64  C=64

    // pooled slabs: A,B,C = 12.8M floats (51.2 MB) each, D = 3.2M floats.
    // All activations/U/V are bf16 (half-occupied granules) — offsets kept.
    constexpr size_t SLOT = (size_t)N0n * Bn * 64;   // 12.8M floats
    constexpr size_t M1 = 1600000;                    // 1.6M-float granule
    float* A = (float*)alloc(SLOT * 4);
    float* B = (float*)alloc(SLOT * 4);
    float* C = (float*)alloc(SLOT * 4);
    float* D = (float*)alloc((size_t)N1n * Bn * 64 * 4);

    // --- CSR build + weight prep ---
    hipMemsetAsync(degcur, 0, (size_t)3 * NT * 4, stream);
    k_wprep<<<256, 256, 0, stream>>>(Wb, Wt0, l0_W1, Wt1, l0_W2, Wt2, l0_Wsk, Wt3,
                                     l1_W1, Wt4, l1_W2, Wt5, l1_Wsk, Wt6, Wf, Wt7);
    k_deg_count<<<(QT + 255) / 256, 256, 0, stream>>>(g0, g1, g2, deg);
    k_scan1<<<NCHUNK, 256, 0, stream>>>(deg, offsets, partials);
    k_scan3<<<(NT + 255) / 256, 256, 0, stream>>>(partials, offsets);
    k_csr_fill<<<(QT + 255) / 256, 256, 0, stream>>>(g0, g1, g2, offsets, cursor, bcur, csr);

    const int nb2 = N0n + N1n;   // g2 node base in offsets
    const int nb1 = N0n;         // g1 node base

    // --- latent -> x0 bf16 [12500,128] @ A[0,M1) ---
    ushort* x0b = (ushort*)A;
    k_latent<<<(N2n + 7) / 8, 256, 0, stream>>>(z, W_up1, b_up1, W_up2, b_up2, x0b);

    // --- conv1 (g2, 128->256): Ub@A[M1,..) Vb@A[3M1,..) -> xc1 bf16 @ A[5M1,..) ---
    ushort* xc1b = (ushort*)(A + 5 * M1);
    k_gemm_mfma<128, 256><<<dim3(196, 8), 256, 0, stream>>>(x0b, Wt0, bb,
                                                            (ushort*)(A + M1), (ushort*)(A + 3 * M1),
                                                            N2n * Bn);
    k_edge_agg<512, 256><<<(N2n + 3) / 4, 256, 0, stream>>>((const ushort*)(A + M1),
                                                            (const ushort*)(A + 3 * M1),
                                                            offsets, csr, nb2, N2n, xc1b);

    // --- l0_W1 (g2, 256->64): -> t1 bf16 @ A[0,M1) (x0 dead) ---
    ushort* t1b = (ushort*)A;
    k_gemm_mfma<256, 64><<<dim3(196, 2), 256, 0, stream>>>(xc1b, Wt1, l0_b1,
                                                           (ushort*)(A + 7 * M1),
                                                           (ushort*)(A + 7 * M1 + 800000),
                                                           N2n * Bn);
    k_edge_agg<128, 768><<<(N2n + 15) / 16, 256, 0, stream>>>((const ushort*)(A + 7 * M1),
                                                              (const ushort*)(A + 7 * M1 + 800000),
                                                              offsets, csr, nb2, N2n, t1b);

    // --- l0_W2 (64->128): U2b@B[0,M1) V2b@B[M1,..) ---
    k_gemm_mfma<64, 128><<<dim3(196, 4), 256, 0, stream>>>(t1b, Wt2, l0_b2,
                                                           (ushort*)B, (ushort*)(B + M1), N2n * Bn);
    // --- skip0 (256->128): Uskb@B[2M1,..) Vskb@B[3M1,..) ---
    k_gemm_mfma<256, 128><<<dim3(196, 4), 256, 0, stream>>>(xc1b, Wt3, l0_bsk,
                                                            (ushort*)(B + 2 * M1), (ushort*)(B + 3 * M1),
                                                            N2n * Bn);
    // --- fused layer0 agg (g1, C=256, nnz=N2n): -> x1 bf16 @ B[4M1,..) ---
    ushort* x1b = (ushort*)(B + 4 * M1);
    k_edge_agg_fused<256, 512><<<(N1n + 7) / 8, 256, 0, stream>>>((const ushort*)B,
                                                                  (const ushort*)(B + M1),
                                                                  (const ushort*)(B + 2 * M1),
                                                                  (const ushort*)(B + 3 * M1),
                                                                  l0_b2, l0_bsk, offsets, cursor, csr,
                                                                  nb1, N1n, N2n, x1b);

    // --- l1_W1 (g1, 128->64): Ub@A[0,..) Vb@A[2M1,..) -> t2 bf16 @ D ---
    ushort* t2b = (ushort*)D;
    k_gemm_mfma<128, 64><<<dim3(782, 2), 256, 0, stream>>>(x1b, Wt4, l1_b1,
                                                           (ushort*)A, (ushort*)(A + 2 * M1), N1n * Bn);
    k_edge_agg<128, 768><<<(N1n + 15) / 16, 256, 0, stream>>>((const ushort*)A,
                                                              (const ushort*)(A + 2 * M1),
                                                              offsets, csr, nb1, N1n, t2b);

    // --- l1_W2 (64->64): U2b@A[0,..) V2b@A[2M1,..) ---
    k_gemm_mfma<64, 64><<<dim3(782, 2), 256, 0, stream>>>(t2b, Wt5, l1_b2,
                                                          (ushort*)A, (ushort*)(A + 2 * M1), N1n * Bn);
    // --- skip1 (128->64): Uskb@A[4M1,..) Vskb@A[6M1,..) ---
    k_gemm_mfma<128, 64><<<dim3(782, 2), 256, 0, stream>>>(x1b, Wt6, l1_bsk,
                                                           (ushort*)(A + 4 * M1), (ushort*)(A + 6 * M1),
                                                           N1n * Bn);
    // --- fused layer1 agg (g0, C=128, nnz=N1n): -> x2 bf16 @ C ---
    ushort* x2b = (ushort*)C;
    k_edge_agg_fused<128, 768><<<(N0n + 15) / 16, 256, 0, stream>>>((const ushort*)A,
                                                                    (const ushort*)(A + 2 * M1),
                                                                    (const ushort*)(A + 4 * M1),
                                                                    (const ushort*)(A + 6 * M1),
                                                                    l1_b2, l1_bsk, offsets, cursor, csr,
                                                                    0, N0n, N1n, x2b);

    // --- final conv (g0, 64->64): x2 -> Ufb bf16 @ A, Vfb bf16 @ B ---
    k_gemm_mfma<64, 64><<<dim3(3125, 2), 256, 0, stream>>>(x2b, Wt7, bf_,
                                                           (ushort*)A, (ushort*)B, N0n * Bn);
    // --- fused final agg + decoder + LN -> d_out ---
    k_agg_dec<<<(N0n + 15) / 16, 256, 0, stream>>>((const ushort*)A, (const ushort*)B, offsets, csr,
                                                   Wd1, bd1, Wd2, bd2, gamma, beta,
                                                   (float*)d_out);
}

// Round 11
// 458.008 us; speedup vs baseline: 1.1311x; 1.0798x over previous
//
#include <hip/hip_runtime.h>
#include <hip/hip_bf16.h>
#include <cstdint>

#define DEV_INLINE __device__ __forceinline__

// problem constants
constexpr int N0n = 100000, N1n = 25000, N2n = 6250;
constexpr int E0n = 800000, E1n = 200000, E2n = 50000;
constexpr int NT  = N0n + N1n + N2n;     // 131250 concatenated node space
constexpr int ET  = E0n + E1n + E2n;     // 1050000 concatenated edge space
constexpr int Bn  = 2;

DEV_INLINE float lrelu(float x) { return x > 0.f ? x : 0.01f * x; }

// r11: (1) rank-based CSR build — k_csr_fill was 67us at 1.7% VALU with 16x
// write amplification (scattered 4B writes x 8 non-coherent XCDs); the atomic
// now lives in a coalesced rank pass, the scatter pass is atomic-free.
// (2) BM=128 GEMM tiles for the 4 big-M GEMMs (8 MFMA/K-step/wave).
DEV_INLINE ushort f2bf(float f) {
    uint32_t u = __builtin_bit_cast(uint32_t, f);
    u += 0x7FFFu + ((u >> 16) & 1u);       // round-to-nearest-even
    return (ushort)(u >> 16);
}
DEV_INLINE float bflo(uint32_t w) { return __builtin_bit_cast(float, w << 16); }
DEV_INLINE float bfhi(uint32_t w) { return __builtin_bit_cast(float, w & 0xFFFF0000u); }
DEV_INLINE uint32_t pack2(float a, float b) {
    return (uint32_t)f2bf(a) | ((uint32_t)f2bf(b) << 16);
}
DEV_INLINE void unpack_bf8(float* u, const uint4 w) {
    u[0] = bflo(w.x); u[1] = bfhi(w.x);
    u[2] = bflo(w.y); u[3] = bfhi(w.y);
    u[4] = bflo(w.z); u[5] = bfhi(w.z);
    u[6] = bflo(w.w); u[7] = bfhi(w.w);
}

// acc[k] += relu(u[k] + v[k]) for 8 bf16 channels packed in a uint4
DEV_INLINE void acc_bf8(float* acc, const float* u, const uint4 w) {
    acc[0] += fmaxf(u[0] + bflo(w.x), 0.f);
    acc[1] += fmaxf(u[1] + bfhi(w.x), 0.f);
    acc[2] += fmaxf(u[2] + bflo(w.y), 0.f);
    acc[3] += fmaxf(u[3] + bfhi(w.y), 0.f);
    acc[4] += fmaxf(u[4] + bflo(w.z), 0.f);
    acc[5] += fmaxf(u[5] + bfhi(w.z), 0.f);
    acc[6] += fmaxf(u[6] + bflo(w.w), 0.f);
    acc[7] += fmaxf(u[7] + bfhi(w.w), 0.f);
}

typedef short bf16x8 __attribute__((ext_vector_type(8)));
typedef float f32x4 __attribute__((ext_vector_type(4)));

// ---------------- CSR build (rank-based, 4 edges/thread) ----------------

constexpr int Q0 = E0n / 4, Q1 = E1n / 4, Q2 = E2n / 4;   // 200000 / 50000 / 12500
constexpr int QT = Q0 + Q1 + Q2;                           // 262500

// Pass 1: one atomic per edge returns rank within (front|back) subset of its
// dst segment; rank + front-bit stored COALESCED. cursor[] ends = valid count.
__global__ __launch_bounds__(256) void k_rank(const int* __restrict__ g0,
                                              const int* __restrict__ g1,
                                              const int* __restrict__ g2,
                                              int* __restrict__ cursor,
                                              int* __restrict__ bcur,
                                              int* __restrict__ rnk) {
    const int q = blockIdx.x * 256 + threadIdx.x;
    int4 sv, dv; int mod_, nb_, thr_, ebase;
    if (q < Q0) {
        sv = *(const int4*)&g0[q * 4]; dv = *(const int4*)&g0[E0n + q * 4];
        mod_ = N0n; nb_ = 0; thr_ = N1n; ebase = q * 4;
    } else if (q < Q0 + Q1) {
        const int lq = q - Q0;
        sv = *(const int4*)&g1[lq * 4]; dv = *(const int4*)&g1[E1n + lq * 4];
        mod_ = N1n; nb_ = N0n; thr_ = N2n; ebase = E0n + lq * 4;
    } else if (q < QT) {
        const int lq = q - Q0 - Q1;
        sv = *(const int4*)&g2[lq * 4]; dv = *(const int4*)&g2[E2n + lq * 4];
        mod_ = N2n; nb_ = N0n + N1n; thr_ = N2n; ebase = E0n + E1n + lq * 4;
    } else return;
    const int ss[4] = {sv.x, sv.y, sv.z, sv.w};
    const int dd[4] = {dv.x, dv.y, dv.z, dv.w};
    int out[4];
#pragma unroll
    for (int i = 0; i < 4; i++) {
        const int src = ss[i] % mod_;
        const int gd = nb_ + dd[i] % mod_;
        const bool front = src < thr_;
        const int r = front ? atomicAdd(&cursor[gd], 1) : atomicAdd(&bcur[gd], 1);
        out[i] = r | (front ? (1 << 30) : 0);
    }
    *(int4*)&rnk[ebase] = int4{out[0], out[1], out[2], out[3]};
}

constexpr int SCAN_CHUNK = 2048;
constexpr int NCHUNK = (NT + SCAN_CHUNK - 1) / SCAN_CHUNK;   // 65

// deg[i] = cursor[i] + bcur[i] (front + back counts)
__global__ __launch_bounds__(256) void k_scan1(const int* __restrict__ cur,
                                               const int* __restrict__ bc,
                                               int* __restrict__ out,
                                               int* __restrict__ partials) {
    __shared__ int sums[256];
    const int chunk = blockIdx.x, t = threadIdx.x;
    const int base = chunk * SCAN_CHUNK + t * 8;
    int v[8]; int s = 0;
#pragma unroll
    for (int i = 0; i < 8; i++) {
        int idx = base + i;
        v[i] = (idx < NT) ? (cur[idx] + bc[idx]) : 0;
        s += v[i];
    }
    int val = s;
    sums[t] = val; __syncthreads();
    for (int off = 1; off < 256; off <<= 1) {
        int y = (t >= off) ? sums[t - off] : 0;
        __syncthreads();
        val += y; sums[t] = val;
        __syncthreads();
    }
    const int excl = val - s;
    if (t == 255) partials[chunk] = val;
    int run = excl;
#pragma unroll
    for (int i = 0; i < 8; i++) { int idx = base + i; if (idx < NT) out[idx] = run; run += v[i]; }
}

// scan2 folded in: each block redundantly prefix-sums the 65 partials in LDS.
__global__ __launch_bounds__(256) void k_scan3(const int* __restrict__ partials,
                                               int* __restrict__ offsets) {
    __shared__ int s[NCHUNK];
    __shared__ int pre[NCHUNK + 1];
    const int t = threadIdx.x;
    if (t < NCHUNK) s[t] = partials[t];
    __syncthreads();
    if (t == 0) {
        int run = 0;
        for (int i = 0; i < NCHUNK; i++) { pre[i] = run; run += s[i]; }
        pre[NCHUNK] = run;
    }
    __syncthreads();
    const int idx = blockIdx.x * 256 + t;
    if (idx < NT) offsets[idx] += pre[idx / SCAN_CHUNK];
    if (idx == 0) offsets[NT] = pre[NCHUNK];   // == ET
}

// Pass 2: atomic-free scatter. pos = front ? offsets[gd]+r : offsets[gd+1]-1-r.
__global__ __launch_bounds__(256) void k_fill2(const int* __restrict__ g0,
                                               const int* __restrict__ g1,
                                               const int* __restrict__ g2,
                                               const int* __restrict__ offsets,
                                               const int* __restrict__ rnk,
                                               int* __restrict__ csr) {
    const int q = blockIdx.x * 256 + threadIdx.x;
    int4 sv, dv; int mod_, nb_, ebase;
    if (q < Q0) {
        sv = *(const int4*)&g0[q * 4]; dv = *(const int4*)&g0[E0n + q * 4];
        mod_ = N0n; nb_ = 0; ebase = q * 4;
    } else if (q < Q0 + Q1) {
        const int lq = q - Q0;
        sv = *(const int4*)&g1[lq * 4]; dv = *(const int4*)&g1[E1n + lq * 4];
        mod_ = N1n; nb_ = N0n; ebase = E0n + lq * 4;
    } else if (q < QT) {
        const int lq = q - Q0 - Q1;
        sv = *(const int4*)&g2[lq * 4]; dv = *(const int4*)&g2[E2n + lq * 4];
        mod_ = N2n; nb_ = N0n + N1n; ebase = E0n + E1n + lq * 4;
    } else return;
    const int4 rv = *(const int4*)&rnk[ebase];
    const int ss[4] = {sv.x, sv.y, sv.z, sv.w};
    const int dd[4] = {dv.x, dv.y, dv.z, dv.w};
    const int rr[4] = {rv.x, rv.y, rv.z, rv.w};
#pragma unroll
    for (int i = 0; i < 4; i++) {
        const int src = ss[i] % mod_;
        const int gd = nb_ + dd[i] % mod_;
        const int r = rr[i] & 0x3FFFFFFF;
        const bool front = (rr[i] >> 30) & 1;
        const int pos = front ? offsets[gd] + r : offsets[gd + 1] - 1 - r;
        if (pos >= 0 && pos < ET) csr[pos] = src;   // local src id
    }
}

// ---------------- weight prep: W[2K][COUT] fp32 -> Wt[2*COUT][K] bf16 ----------------

__global__ __launch_bounds__(256) void k_wprep(const float* W0, ushort* T0,
                                               const float* W1, ushort* T1,
                                               const float* W2, ushort* T2,
                                               const float* W3, ushort* T3,
                                               const float* W4, ushort* T4,
                                               const float* W5, ushort* T5,
                                               const float* W6, ushort* T6,
                                               const float* W7, ushort* T7) {
    constexpr int KS[8] = {128, 256, 64, 256, 128, 64, 128, 64};
    constexpr int CS[8] = {256, 64, 128, 128, 64, 64, 64, 64};
    const int set = blockIdx.x >> 5;          // 32 blocks / set
    const int blk = blockIdx.x & 31;
    const float* W; ushort* T;
    switch (set) {
        case 0: W = W0; T = T0; break;
        case 1: W = W1; T = T1; break;
        case 2: W = W2; T = T2; break;
        case 3: W = W3; T = T3; break;
        case 4: W = W4; T = T4; break;
        case 5: W = W5; T = T5; break;
        case 6: W = W6; T = T6; break;
        default: W = W7; T = T7; break;
    }
    const int K = KS[set], C = CS[set];
    const int tot = 2 * C * K;
    for (int idx = blk * 256 + threadIdx.x; idx < tot; idx += 32 * 256) {
        const int n = idx / K, k = idx % K;
        float v;
        if (n < C) v = W[(size_t)k * C + n] - W[(size_t)(K + k) * C + n];
        else       v = W[(size_t)(K + k) * C + (n - C)];
        T[idx] = f2bf(v);
    }
}

// ---------------- latent MLP: z -> x0 bf16 [N2*B, 128] ----------------

__global__ __launch_bounds__(256) void k_latent(const float* __restrict__ z,
                                                const float* __restrict__ W1,
                                                const float* __restrict__ b1,
                                                const float* __restrict__ W2,
                                                const float* __restrict__ b2,
                                                ushort* __restrict__ x0b) {
    __shared__ float col[64];
    const int t = threadIdx.x;
    const int b = t >> 7, l = t & 127;
    const float zv = z[b * 128 + l];
    float h1[64];
#pragma unroll
    for (int k = 0; k < 64; k++) h1[k] = lrelu(zv * W1[k] + b1[k]);
    for (int nn = 0; nn < 8; nn++) {
        const int n = blockIdx.x * 8 + nn;
        if (n >= N2n) break;                 // uniform across block
        if (t < 64) col[t] = W2[t * N2n + n];
        __syncthreads();
        float s = b2[n];
#pragma unroll
        for (int k = 0; k < 64; k++) s += h1[k] * col[k];
        x0b[((size_t)n * Bn + b) * 128 + l] = f2bf(s);
        __syncthreads();
    }
}

// ---------------- MFMA GEMM: D = x_bf @ [Wd | Wb]; U bf16 (+bias), V bf16 ----------
// 4 waves = 2x2 wave grid; wave tile = (BM/2)x32 via (BM/32)x2 16x16x32 frags.
// BM=64 for small-M (occupancy first, r7), BM=128 for big-M (8 MFMA/K-step/wave).

template <int K, int COUT, int BM>
__global__ __launch_bounds__(256) void k_gemm_mfma(const ushort* __restrict__ xb,
                                                   const ushort* __restrict__ Wt,
                                                   const float* __restrict__ bias,
                                                   ushort* __restrict__ Ub,
                                                   ushort* __restrict__ Vb,
                                                   int Mrows) {
    constexpr int FI = BM / 32;              // row frags per wave
    __shared__ ushort As[BM][40];
    const int t = threadIdx.x;
    const int lane = t & 63;
    const int wave = t >> 6;
    const int wr = wave >> 1, wc = wave & 1;
    const int row0 = blockIdx.x * BM;
    const int col0 = blockIdx.y * 64;        // in [0, 2*COUT)
    const int l15 = lane & 15;
    const int kg = lane >> 4;                // 0..3
    f32x4 acc[FI][2] = {};

    for (int k0 = 0; k0 < K; k0 += 32) {
        __syncthreads();
        if constexpr (BM == 64) {            // 4 thr/row, 1 uint4 each
            const int srow = t >> 2, sseg = (t & 3) * 8;
            uint4 a = {0, 0, 0, 0};
            const int gr = row0 + srow;
            if (gr < Mrows) a = *(const uint4*)&xb[(size_t)gr * K + k0 + sseg];
            *(uint4*)&As[srow][sseg] = a;
        } else {                             // BM=128: 2 thr/row, 2 uint4 each
            const int srow = t >> 1, sseg = (t & 1) * 16;
            uint4 a0 = {0, 0, 0, 0}, a1 = {0, 0, 0, 0};
            const int gr = row0 + srow;
            if (gr < Mrows) {
                a0 = *(const uint4*)&xb[(size_t)gr * K + k0 + sseg];
                a1 = *(const uint4*)&xb[(size_t)gr * K + k0 + sseg + 8];
            }
            *(uint4*)&As[srow][sseg] = a0;
            *(uint4*)&As[srow][sseg + 8] = a1;
        }
        __syncthreads();
        bf16x8 af[FI], bfr[2];
#pragma unroll
        for (int fi = 0; fi < FI; fi++)
            af[fi] = *(const bf16x8*)&As[wr * (BM / 2) + fi * 16 + l15][kg * 8];
#pragma unroll
        for (int fj = 0; fj < 2; fj++) {
            const int c = col0 + wc * 32 + fj * 16 + l15;
            bfr[fj] = *(const bf16x8*)&Wt[(size_t)c * K + k0 + kg * 8];
        }
#pragma unroll
        for (int fi = 0; fi < FI; fi++)
#pragma unroll
            for (int fj = 0; fj < 2; fj++)
                acc[fi][fj] = __builtin_amdgcn_mfma_f32_16x16x32_bf16(
                    af[fi], bfr[fj], acc[fi][fj], 0, 0, 0);
    }
    // D layout (m89-verified): col = lane&15, row = (lane>>4)*4 + reg
    const bool isU = col0 < COUT;
#pragma unroll
    for (int fi = 0; fi < FI; fi++) {
#pragma unroll
        for (int fj = 0; fj < 2; fj++) {
            const int c = col0 + wc * 32 + fj * 16 + l15;
#pragma unroll
            for (int r = 0; r < 4; r++) {
                const int row = row0 + wr * (BM / 2) + fi * 16 + kg * 4 + r;
                if (row < Mrows) {
                    if (isU) Ub[(size_t)row * COUT + c] = f2bf(acc[fi][fj][r] + bias[c]);
                    else     Vb[(size_t)row * COUT + (c - COUT)] = f2bf(acc[fi][fj][r]);
                }
            }
        }
    }
}

// ---------------- dense edge agg: out_bf16[i] = mean_j relu(u_i + v_j) ------------
// bf16 U + V, 8 ch/lane, LDS-staged csr, block-uniform fast path, 4-wide batch.

template <int C, int CAP>
__global__ __launch_bounds__(256) void k_edge_agg(const ushort* __restrict__ Ub,
                                                  const ushort* __restrict__ Vb,
                                                  const int* __restrict__ offsets,
                                                  const int* __restrict__ csr,
                                                  int nbase, int nnodes,
                                                  ushort* __restrict__ outb) {
    constexpr int TPN = C / 8;          // lanes per node (8 bf16 ch each)
    constexpr int NPB = 256 / TPN;      // nodes per block
    __shared__ int soff[NPB + 1];
    __shared__ int scsr[CAP];
    const int t = threadIdx.x;
    const int n0 = blockIdx.x * NPB;
    if (t <= NPB) {
        const int idx = min(n0 + t, nnodes);
        soff[t] = max(0, min(offsets[nbase + idx], ET));
    }
    __syncthreads();
    const int base = soff[0];
    const int span = soff[NPB] - base;
    const int tot = min(span, CAP);
    for (int k = t; k < tot; k += 256) scsr[k] = csr[base + k];
    __syncthreads();
    const bool allin = span <= CAP;     // block-uniform

    const int sub = t / TPN;
    const int c8 = (t % TPN) * 8;
    const int i = n0 + sub;
    if (i >= nnodes) return;
    const int beg = soff[sub];
    const int end = max(soff[sub + 1], beg);
    float u[8], acc[8] = {};
    unpack_bf8(u, *(const uint4*)&Ub[(size_t)i * C + c8]);
    if (allin) {
        int o = beg - base;
        const int oend = end - base;
        for (; o + 4 <= oend; o += 4) {          // 4-wide: stays under VGPR cliff
            const int j0 = scsr[o], j1 = scsr[o + 1], j2 = scsr[o + 2], j3 = scsr[o + 3];
            const uint4 w0 = *(const uint4*)&Vb[(size_t)j0 * C + c8];
            const uint4 w1 = *(const uint4*)&Vb[(size_t)j1 * C + c8];
            const uint4 w2 = *(const uint4*)&Vb[(size_t)j2 * C + c8];
            const uint4 w3 = *(const uint4*)&Vb[(size_t)j3 * C + c8];
            acc_bf8(acc, u, w0); acc_bf8(acc, u, w1);
            acc_bf8(acc, u, w2); acc_bf8(acc, u, w3);
        }
        for (; o < oend; ++o)
            acc_bf8(acc, u, *(const uint4*)&Vb[(size_t)scsr[o] * C + c8]);
    } else {
        for (int e = beg; e < end; ++e)
            acc_bf8(acc, u, *(const uint4*)&Vb[(size_t)csr[e] * C + c8]);
    }
    const int dg = end - beg;
    const float inv = 1.f / (float)(dg > 0 ? dg : 1);
    uint4 o;
    o.x = pack2(acc[0] * inv, acc[1] * inv);
    o.y = pack2(acc[2] * inv, acc[3] * inv);
    o.z = pack2(acc[4] * inv, acc[5] * inv);
    o.w = pack2(acc[6] * inv, acc[7] * inv);
    *(uint4*)&outb[(size_t)i * C + c8] = o;
}

// ---------------- fused dual agg (Res_up output), bf16 U/V, fast path -------------
// Partitioned CSR: [beg, beg+vc) valid gathers; remaining cnt edges -> cnt*relu(u).

template <int C, int CAP>
__global__ __launch_bounds__(256) void k_edge_agg_fused(const ushort* __restrict__ U2b,
                                                        const ushort* __restrict__ V2b,
                                                        const ushort* __restrict__ Uskb,
                                                        const ushort* __restrict__ Vskb,
                                                        const float* __restrict__ b2,
                                                        const float* __restrict__ bsk,
                                                        const int* __restrict__ offsets,
                                                        const int* __restrict__ vcnt,
                                                        const int* __restrict__ csr,
                                                        int nbase, int nnodes, int nnz,
                                                        ushort* __restrict__ outb) {
    constexpr int COUTc = C / Bn;
    constexpr int TPN = C / 8;
    constexpr int NPB = 256 / TPN;
    __shared__ int soff[NPB + 1];
    __shared__ int svc[NPB];
    __shared__ int scsr[CAP];
    const int t = threadIdx.x;
    const int n0 = blockIdx.x * NPB;
    if (t <= NPB) {
        const int idx = min(n0 + t, nnodes);
        soff[t] = max(0, min(offsets[nbase + idx], ET));
    }
    if (t < NPB) svc[t] = (n0 + t < nnodes) ? vcnt[nbase + n0 + t] : 0;
    __syncthreads();
    const int base = soff[0];
    const int span = soff[NPB] - base;
    const int tot = min(span, CAP);
    for (int k = t; k < tot; k += 256) scsr[k] = csr[base + k];
    __syncthreads();
    const bool allin = span <= CAP;     // block-uniform

    const int sub = t / TPN;
    const int c8 = (t % TPN) * 8;
    const int i = n0 + sub;
    if (i >= nnodes) return;
    const int beg = soff[sub];
    const int end = max(soff[sub + 1], beg);
    const int dg = end - beg;
    const int vc = max(0, min(svc[sub], dg));
    const int cb = c8 & (COUTc - 1);
    float u2[8], usk[8];
    if (i < nnz) {
        unpack_bf8(u2,  *(const uint4*)&U2b[(size_t)i * C + c8]);
        unpack_bf8(usk, *(const uint4*)&Uskb[(size_t)i * C + c8]);
    } else {
        *(float4*)&u2[0]  = *(const float4*)&b2[cb];
        *(float4*)&u2[4]  = *(const float4*)&b2[cb + 4];
        *(float4*)&usk[0] = *(const float4*)&bsk[cb];
        *(float4*)&usk[4] = *(const float4*)&bsk[cb + 4];
    }
    float a2[8] = {}, ask[8] = {};
    if (allin) {
        int o = beg - base;
        const int oend = o + vc;
        for (; o + 2 <= oend; o += 2) {          // 2x2 tables = 4 gathers in flight
            const int j0 = scsr[o], j1 = scsr[o + 1];
            const uint4 p0 = *(const uint4*)&V2b[(size_t)j0 * C + c8];
            const uint4 p1 = *(const uint4*)&V2b[(size_t)j1 * C + c8];
            const uint4 q0 = *(const uint4*)&Vskb[(size_t)j0 * C + c8];
            const uint4 q1 = *(const uint4*)&Vskb[(size_t)j1 * C + c8];
            acc_bf8(a2, u2, p0); acc_bf8(a2, u2, p1);
            acc_bf8(ask, usk, q0); acc_bf8(ask, usk, q1);
        }
        for (; o < oend; ++o) {
            const int j = scsr[o];
            acc_bf8(a2, u2, *(const uint4*)&V2b[(size_t)j * C + c8]);
            acc_bf8(ask, usk, *(const uint4*)&Vskb[(size_t)j * C + c8]);
        }
    } else {
        for (int e = beg; e < beg + vc; ++e) {
            const int j = csr[e];
            acc_bf8(a2, u2, *(const uint4*)&V2b[(size_t)j * C + c8]);
            acc_bf8(ask, usk, *(const uint4*)&Vskb[(size_t)j * C + c8]);
        }
    }
    const int cnt = dg - vc;                  // edges with j >= nnz: v = 0
    if (cnt > 0) {
        const float fc = (float)cnt;
#pragma unroll
        for (int k = 0; k < 8; k++) {
            a2[k]  += fc * fmaxf(u2[k], 0.f);
            ask[k] += fc * fmaxf(usk[k], 0.f);
        }
    }
    const float inv = 1.f / (float)(dg > 0 ? dg : 1);
    float ov[8];
#pragma unroll
    for (int k = 0; k < 8; k++) ov[k] = lrelu((a2[k] + ask[k]) * inv);
    uint4 o;
    o.x = pack2(ov[0], ov[1]); o.y = pack2(ov[2], ov[3]);
    o.z = pack2(ov[4], ov[5]); o.w = pack2(ov[6], ov[7]);
    *(uint4*)&outb[(size_t)i * C + c8] = o;
}

// ---------------- fused final agg + decoder MLP + LayerNorm(3) ----------------
// 16 nodes/block, 16 lanes/node, bf16 U/V, LDS-csr fast path, 4-wide batch.

__global__ __launch_bounds__(256) void k_agg_dec(const ushort* __restrict__ Ub,
                                                 const ushort* __restrict__ Vb,
                                                 const int* __restrict__ offsets,
                                                 const int* __restrict__ csr,
                                                 const float* __restrict__ Wd1,
                                                 const float* __restrict__ bd1,
                                                 const float* __restrict__ Wd2,
                                                 const float* __restrict__ bd2,
                                                 const float* __restrict__ gamma,
                                                 const float* __restrict__ beta,
                                                 float* __restrict__ out) {
    constexpr int C = 128;
    constexpr int CAP = 768;
    __shared__ float w1[2048];          // Wd1 [64,32]
    __shared__ float w2[96];            // Wd2 [32,3]
    __shared__ float sb1[32], sb2[3], sg[3], sbt[3];
    __shared__ float xs[32 * 66];       // 32 (n,b) rows of 64, stride 66
    __shared__ float hs[32][33];        // h1 per row
    __shared__ int soff[17];
    __shared__ int scsr[CAP];
    const int t = threadIdx.x;
    for (int i = t; i < 2048; i += 256) w1[i] = Wd1[i];
    if (t < 96) w2[t] = Wd2[t];
    if (t < 32) sb1[t] = bd1[t];
    if (t < 3) { sb2[t] = bd2[t]; sg[t] = gamma[t]; sbt[t] = beta[t]; }

    const int n0 = blockIdx.x * 16;
    if (t <= 16) {
        const int idx = min(n0 + t, N0n);
        soff[t] = max(0, min(offsets[idx], ET));
    }
    __syncthreads();
    const int base = soff[0];
    const int span = soff[16] - base;
    const int tot = min(span, CAP);
    for (int k = t; k < tot; k += 256) scsr[k] = csr[base + k];
    __syncthreads();
    const bool allin = span <= CAP;     // block-uniform

    // --- agg phase: 16 nodes/block, 16 thr/node, 8 bf16 ch/lane ---
    const int sub = t >> 4;
    const int c8 = (t & 15) * 8;        // channel = b*64 + k
    const int i0 = n0 + sub;
    float r[8] = {};
    if (i0 < N0n) {
        const int beg = soff[sub];
        const int end = max(soff[sub + 1], beg);
        float u[8], acc[8] = {};
        unpack_bf8(u, *(const uint4*)&Ub[(size_t)i0 * C + c8]);
        if (allin) {
            int o = beg - base;
            const int oend = end - base;
            for (; o + 4 <= oend; o += 4) {      // 4-wide: stays under VGPR cliff
                const int j0 = scsr[o], j1 = scsr[o + 1], j2 = scsr[o + 2], j3 = scsr[o + 3];
                const uint4 w0 = *(const uint4*)&Vb[(size_t)j0 * C + c8];
                const uint4 w1v = *(const uint4*)&Vb[(size_t)j1 * C + c8];
                const uint4 w2v = *(const uint4*)&Vb[(size_t)j2 * C + c8];
                const uint4 w3 = *(const uint4*)&Vb[(size_t)j3 * C + c8];
                acc_bf8(acc, u, w0); acc_bf8(acc, u, w1v);
                acc_bf8(acc, u, w2v); acc_bf8(acc, u, w3);
            }
            for (; o < oend; ++o)
                acc_bf8(acc, u, *(const uint4*)&Vb[(size_t)scsr[o] * C + c8]);
        } else {
            for (int e = beg; e < end; ++e)
                acc_bf8(acc, u, *(const uint4*)&Vb[(size_t)csr[e] * C + c8]);
        }
        const int dg = end - beg;
        const float inv = 1.f / (float)(dg > 0 ? dg : 1);
#pragma unroll
        for (int k = 0; k < 8; k++) r[k] = acc[k] * inv;
    }
    // stage into LDS: row = sub*2 + b, col = k (8 entries per lane)
    {
        const int rrow = sub * 2 + (c8 >> 6);
        const int rk = c8 & 63;
        float* xp = &xs[rrow * 66 + rk];
#pragma unroll
        for (int k = 0; k < 8; k++) xp[k] = r[k];
    }
    __syncthreads();

    // --- decoder: 32 rows x 8 threads; thread computes h1[l8+8m], m=0..3 ---
    const int drow = t >> 3;
    const int l8 = t & 7;
    float h1[4] = {sb1[l8], sb1[l8 + 8], sb1[l8 + 16], sb1[l8 + 24]};
    const float* xrow = &xs[drow * 66];
#pragma unroll 8
    for (int k = 0; k < 64; k++) {
        const float xk = xrow[k];
        h1[0] += xk * w1[k * 32 + l8];
        h1[1] += xk * w1[k * 32 + l8 + 8];
        h1[2] += xk * w1[k * 32 + l8 + 16];
        h1[3] += xk * w1[k * 32 + l8 + 24];
    }
    hs[drow][l8]      = lrelu(h1[0]);
    hs[drow][l8 + 8]  = lrelu(h1[1]);
    hs[drow][l8 + 16] = lrelu(h1[2]);
    hs[drow][l8 + 24] = lrelu(h1[3]);
    __syncthreads();

    // --- h2 + LN: one thread per row ---
    if (t < 32) {
        const int node = t >> 1, b = t & 1;
        const int n = n0 + node;
        if (n < N0n) {
            float h2[3];
#pragma unroll
            for (int j = 0; j < 3; j++) {
                float s = sb2[j];
#pragma unroll
                for (int c = 0; c < 32; c++) s += hs[t][c] * w2[c * 3 + j];
                h2[j] = s;
            }
            const float mu = (h2[0] + h2[1] + h2[2]) * (1.f / 3.f);
            const float d0 = h2[0] - mu, d1 = h2[1] - mu, d2 = h2[2] - mu;
            const float var = (d0 * d0 + d1 * d1 + d2 * d2) * (1.f / 3.f);
            const float inv = rsqrtf(var + 1e-5f);
            const size_t ob = (size_t)b * N0n * 3 + (size_t)n * 3;
            out[ob + 0] = d0 * inv * sg[0] + sbt[0];
            out[ob + 1] = d1 * inv * sg[1] + sbt[1];
            out[ob + 2] = d2 * inv * sg[2] + sbt[2];
        }
    }
}

// ---------------- launch ----------------

extern "C" void kernel_launch(void* const* d_in, const int* in_sizes, int n_in,
                              void* d_out, int out_size, void* d_ws, size_t ws_size,
                              hipStream_t stream) {
    (void)in_sizes; (void)n_in; (void)out_size; (void)ws_size;
    const float* z   = (const float*)d_in[0];
    const int* g0    = (const int*)d_in[1];
    const int* g1    = (const int*)d_in[2];
    const int* g2    = (const int*)d_in[3];
    const float* W_up1 = (const float*)d_in[6];
    const float* b_up1 = (const float*)d_in[7];
    const float* W_up2 = (const float*)d_in[8];
    const float* b_up2 = (const float*)d_in[9];
    const float* Wb    = (const float*)d_in[10];
    const float* bb    = (const float*)d_in[11];
    const float* l0_W1 = (const float*)d_in[12];
    const float* l0_b1 = (const float*)d_in[13];
    const float* l0_W2 = (const float*)d_in[14];
    const float* l0_b2 = (const float*)d_in[15];
    const float* l0_Wsk = (const float*)d_in[16];
    const float* l0_bsk = (const float*)d_in[17];
    const float* l1_W1 = (const float*)d_in[18];
    const float* l1_b1 = (const float*)d_in[19];
    const float* l1_W2 = (const float*)d_in[20];
    const float* l1_b2 = (const float*)d_in[21];
    const float* l1_Wsk = (const float*)d_in[22];
    const float* l1_bsk = (const float*)d_in[23];
    const float* Wf    = (const float*)d_in[24];
    const float* bf_   = (const float*)d_in[25];
    const float* Wd1   = (const float*)d_in[26];
    const float* bd1   = (const float*)d_in[27];
    const float* Wd2   = (const float*)d_in[28];
    const float* bd2   = (const float*)d_in[29];
    const float* gamma = (const float*)d_in[30];
    const float* beta  = (const float*)d_in[31];

    char* p = (char*)d_ws;
    auto alloc = [&](size_t bytes) -> char* {
        char* r = p; p += (bytes + 255) & ~(size_t)255; return r;
    };
    int* offsets  = (int*)alloc((size_t)(NT + 1) * 4);
    int* partials = (int*)alloc((size_t)NCHUNK * 4);
    int* degcur   = (int*)alloc((size_t)2 * NT * 4);
    int* cursor = degcur; int* bcur = degcur + NT;
    int* csr = (int*)alloc((size_t)ET * 4);
    int* rnk = (int*)alloc((size_t)ET * 4);

    // bf16 weight buffers (Wt[2*COUT][K]) for the 8 MFMA GEMMs
    ushort* Wt0 = (ushort*)alloc(65536 * 2);   // conv1  K=128 C=256
    ushort* Wt1 = (ushort*)alloc(32768 * 2);   // l0_W1  K=256 C=64
    ushort* Wt2 = (ushort*)alloc(16384 * 2);   // l0_W2  K=64  C=128
    ushort* Wt3 = (ushort*)alloc(65536 * 2);   // skip0  K=256 C=128
    ushort* Wt4 = (ushort*)alloc(16384 * 2);   // l1_W1  K=128 C=64
    ushort* Wt5 = (ushort*)alloc(8192 * 2);    // l1_W2  K=64  C=64
    ushort* Wt6 = (ushort*)alloc(16384 * 2);   // skip1  K=128 C=64
    ushort* Wt7 = (ushort*)alloc(8192 * 2);    // final  K=64  C=64

    // pooled slabs: A,B,C = 12.8M floats (51.2 MB) each, D = 3.2M floats.
    // All activations/U/V are bf16 (half-occupied granules) — offsets kept.
    constexpr size_t SLOT = (size_t)N0n * Bn * 64;   // 12.8M floats
    constexpr size_t M1 = 1600000;                    // 1.6M-float granule
    float* A = (float*)alloc(SLOT * 4);
    float* B = (float*)alloc(SLOT * 4);
    float* C = (float*)alloc(SLOT * 4);
    float* D = (float*)alloc((size_t)N1n * Bn * 64 * 4);

    // --- CSR build (rank-based) + weight prep ---
    hipMemsetAsync(degcur, 0, (size_t)2 * NT * 4, stream);
    k_wprep<<<256, 256, 0, stream>>>(Wb, Wt0, l0_W1, Wt1, l0_W2, Wt2, l0_Wsk, Wt3,
                                     l1_W1, Wt4, l1_W2, Wt5, l1_Wsk, Wt6, Wf, Wt7);
    k_rank<<<(QT + 255) / 256, 256, 0, stream>>>(g0, g1, g2, cursor, bcur, rnk);
    k_scan1<<<NCHUNK, 256, 0, stream>>>(cursor, bcur, offsets, partials);
    k_scan3<<<(NT + 255) / 256, 256, 0, stream>>>(partials, offsets);
    k_fill2<<<(QT + 255) / 256, 256, 0, stream>>>(g0, g1, g2, offsets, rnk, csr);

    const int nb2 = N0n + N1n;   // g2 node base in offsets
    const int nb1 = N0n;         // g1 node base

    // --- latent -> x0 bf16 [12500,128] @ A[0,M1) ---
    ushort* x0b = (ushort*)A;
    k_latent<<<(N2n + 7) / 8, 256, 0, stream>>>(z, W_up1, b_up1, W_up2, b_up2, x0b);

    // --- conv1 (g2, 128->256): Ub@A[M1,..) Vb@A[3M1,..) -> xc1 bf16 @ A[5M1,..) ---
    ushort* xc1b = (ushort*)(A + 5 * M1);
    k_gemm_mfma<128, 256, 64><<<dim3(196, 8), 256, 0, stream>>>(x0b, Wt0, bb,
                                                                (ushort*)(A + M1), (ushort*)(A + 3 * M1),
                                                                N2n * Bn);
    k_edge_agg<512, 256><<<(N2n + 3) / 4, 256, 0, stream>>>((const ushort*)(A + M1),
                                                            (const ushort*)(A + 3 * M1),
                                                            offsets, csr, nb2, N2n, xc1b);

    // --- l0_W1 (g2, 256->64): -> t1 bf16 @ A[0,M1) (x0 dead) ---
    ushort* t1b = (ushort*)A;
    k_gemm_mfma<256, 64, 64><<<dim3(196, 2), 256, 0, stream>>>(xc1b, Wt1, l0_b1,
                                                               (ushort*)(A + 7 * M1),
                                                               (ushort*)(A + 7 * M1 + 800000),
                                                               N2n * Bn);
    k_edge_agg<128, 768><<<(N2n + 15) / 16, 256, 0, stream>>>((const ushort*)(A + 7 * M1),
                                                              (const ushort*)(A + 7 * M1 + 800000),
                                                              offsets, csr, nb2, N2n, t1b);

    // --- l0_W2 (64->128): U2b@B[0,M1) V2b@B[M1,..) ---
    k_gemm_mfma<64, 128, 64><<<dim3(196, 4), 256, 0, stream>>>(t1b, Wt2, l0_b2,
                                                               (ushort*)B, (ushort*)(B + M1), N2n * Bn);
    // --- skip0 (256->128): Uskb@B[2M1,..) Vskb@B[3M1,..) ---
    k_gemm_mfma<256, 128, 64><<<dim3(196, 4), 256, 0, stream>>>(xc1b, Wt3, l0_bsk,
                                                                (ushort*)(B + 2 * M1), (ushort*)(B + 3 * M1),
                                                                N2n * Bn);
    // --- fused layer0 agg (g1, C=256, nnz=N2n): -> x1 bf16 @ B[4M1,..) ---
    ushort* x1b = (ushort*)(B + 4 * M1);
    k_edge_agg_fused<256, 512><<<(N1n + 7) / 8, 256, 0, stream>>>((const ushort*)B,
                                                                  (const ushort*)(B + M1),
                                                                  (const ushort*)(B + 2 * M1),
                                                                  (const ushort*)(B + 3 * M1),
                                                                  l0_b2, l0_bsk, offsets, cursor, csr,
                                                                  nb1, N1n, N2n, x1b);

    // --- l1_W1 (g1, 128->64): Ub@A[0,..) Vb@A[2M1,..) -> t2 bf16 @ D ---
    ushort* t2b = (ushort*)D;
    k_gemm_mfma<128, 64, 128><<<dim3(391, 2), 256, 0, stream>>>(x1b, Wt4, l1_b1,
                                                                (ushort*)A, (ushort*)(A + 2 * M1),
                                                                N1n * Bn);
    k_edge_agg<128, 768><<<(N1n + 15) / 16, 256, 0, stream>>>((const ushort*)A,
                                                              (const ushort*)(A + 2 * M1),
                                                              offsets, csr, nb1, N1n, t2b);

    // --- l1_W2 (64->64): U2b@A[0,..) V2b@A[2M1,..) ---
    k_gemm_mfma<64, 64, 128><<<dim3(391, 2), 256, 0, stream>>>(t2b, Wt5, l1_b2,
                                                               (ushort*)A, (ushort*)(A + 2 * M1),
                                                               N1n * Bn);
    // --- skip1 (128->64): Uskb@A[4M1,..) Vskb@A[6M1,..) ---
    k_gemm_mfma<128, 64, 128><<<dim3(391, 2), 256, 0, stream>>>(x1b, Wt6, l1_bsk,
                                                                (ushort*)(A + 4 * M1), (ushort*)(A + 6 * M1),
                                                                N1n * Bn);
    // --- fused layer1 agg (g0, C=128, nnz=N1n): -> x2 bf16 @ C ---
    ushort* x2b = (ushort*)C;
    k_edge_agg_fused<128, 768><<<(N0n + 15) / 16, 256, 0, stream>>>((const ushort*)A,
                                                                    (const ushort*)(A + 2 * M1),
                                                                    (const ushort*)(A + 4 * M1),
                                                                    (const ushort*)(A + 6 * M1),
                                                                    l1_b2, l1_bsk, offsets, cursor, csr,
                                                                    0, N0n, N1n, x2b);

    // --- final conv (g0, 64->64): x2 -> Ufb bf16 @ A, Vfb bf16 @ B ---
    k_gemm_mfma<64, 64, 128><<<dim3(1563, 2), 256, 0, stream>>>(x2b, Wt7, bf_,
                                                                (ushort*)A, (ushort*)B, N0n * Bn);
    // --- fused final agg + decoder + LN -> d_out ---
    k_agg_dec<<<(N0n + 15) / 16, 256, 0, stream>>>((const ushort*)A, (const ushort*)B, offsets, csr,
                                                   Wd1, bd1, Wd2, bd2, gamma, beta,
                                                   (float*)d_out);
}

// Round 12
// 420.592 us; speedup vs baseline: 1.2317x; 1.0890x over previous
//
#include <hip/hip_runtime.h>
#include <hip/hip_bf16.h>
#include <cstdint>

#define DEV_INLINE __device__ __forceinline__

// problem constants
constexpr int N0n = 100000, N1n = 25000, N2n = 6250;
constexpr int E0n = 800000, E1n = 200000, E2n = 50000;
constexpr int NT  = N0n + N1n + N2n;     // 131250 concatenated node space
constexpr int ET  = E0n + E1n + E2n;     // 1050000 concatenated edge space
constexpr int Bn  = 2;

DEV_INLINE float lrelu(float x) { return x > 0.f ? x : 0.01f * x; }

// r12: launch-count consolidation (21 -> 16) + GEMM pair-merges, bitwise-same
// math. All GEMMs write one [M][NTOT] matrix with concat bias (0 in V regions);
// l0_W1+skip0 and l1_W1+skip1 merged (shared input read once); independent ops
// batched into fat kernels ([rank|wprep|bias|latent], [fill2|conv1-GEMM]).
DEV_INLINE ushort f2bf(float f) {
    uint32_t u = __builtin_bit_cast(uint32_t, f);
    u += 0x7FFFu + ((u >> 16) & 1u);       // round-to-nearest-even
    return (ushort)(u >> 16);
}
DEV_INLINE float bflo(uint32_t w) { return __builtin_bit_cast(float, w << 16); }
DEV_INLINE float bfhi(uint32_t w) { return __builtin_bit_cast(float, w & 0xFFFF0000u); }
DEV_INLINE uint32_t pack2(float a, float b) {
    return (uint32_t)f2bf(a) | ((uint32_t)f2bf(b) << 16);
}
DEV_INLINE void unpack_bf8(float* u, const uint4 w) {
    u[0] = bflo(w.x); u[1] = bfhi(w.x);
    u[2] = bflo(w.y); u[3] = bfhi(w.y);
    u[4] = bflo(w.z); u[5] = bfhi(w.z);
    u[6] = bflo(w.w); u[7] = bfhi(w.w);
}
DEV_INLINE void acc_bf8(float* acc, const float* u, const uint4 w) {
    acc[0] += fmaxf(u[0] + bflo(w.x), 0.f);
    acc[1] += fmaxf(u[1] + bfhi(w.x), 0.f);
    acc[2] += fmaxf(u[2] + bflo(w.y), 0.f);
    acc[3] += fmaxf(u[3] + bfhi(w.y), 0.f);
    acc[4] += fmaxf(u[4] + bflo(w.z), 0.f);
    acc[5] += fmaxf(u[5] + bfhi(w.z), 0.f);
    acc[6] += fmaxf(u[6] + bflo(w.w), 0.f);
    acc[7] += fmaxf(u[7] + bfhi(w.w), 0.f);
}

typedef short bf16x8 __attribute__((ext_vector_type(8)));
typedef float f32x4 __attribute__((ext_vector_type(4)));

// ---------------- CSR build constants ----------------

constexpr int Q0 = E0n / 4, Q1 = E1n / 4, Q2 = E2n / 4;
constexpr int QT = Q0 + Q1 + Q2;                           // 262500
constexpr int RB = (QT + 255) / 256;                       // 1026 rank blocks
constexpr int WB = 192;                                    // 6 sets x 32 blocks
constexpr int LB = (N2n + 7) / 8;                          // 782 latent blocks
constexpr int FB = RB;                                     // fill2 blocks

constexpr int SCAN_CHUNK = 2048;
constexpr int NCHUNK = (NT + SCAN_CHUNK - 1) / SCAN_CHUNK;   // 65

// ---------------- scan kernels (unchanged) ----------------

__global__ __launch_bounds__(256) void k_scan1(const int* __restrict__ cur,
                                               const int* __restrict__ bc,
                                               int* __restrict__ out,
                                               int* __restrict__ partials) {
    __shared__ int sums[256];
    const int chunk = blockIdx.x, t = threadIdx.x;
    const int base = chunk * SCAN_CHUNK + t * 8;
    int v[8]; int s = 0;
#pragma unroll
    for (int i = 0; i < 8; i++) {
        int idx = base + i;
        v[i] = (idx < NT) ? (cur[idx] + bc[idx]) : 0;
        s += v[i];
    }
    int val = s;
    sums[t] = val; __syncthreads();
    for (int off = 1; off < 256; off <<= 1) {
        int y = (t >= off) ? sums[t - off] : 0;
        __syncthreads();
        val += y; sums[t] = val;
        __syncthreads();
    }
    const int excl = val - s;
    if (t == 255) partials[chunk] = val;
    int run = excl;
#pragma unroll
    for (int i = 0; i < 8; i++) { int idx = base + i; if (idx < NT) out[idx] = run; run += v[i]; }
}

__global__ __launch_bounds__(256) void k_scan3(const int* __restrict__ partials,
                                               int* __restrict__ offsets) {
    __shared__ int s[NCHUNK];
    __shared__ int pre[NCHUNK + 1];
    const int t = threadIdx.x;
    if (t < NCHUNK) s[t] = partials[t];
    __syncthreads();
    if (t == 0) {
        int run = 0;
        for (int i = 0; i < NCHUNK; i++) { pre[i] = run; run += s[i]; }
        pre[NCHUNK] = run;
    }
    __syncthreads();
    const int idx = blockIdx.x * 256 + t;
    if (idx < NT) offsets[idx] += pre[idx / SCAN_CHUNK];
    if (idx == 0) offsets[NT] = pre[NCHUNK];   // == ET
}

// ---------------- GEMM device body: P[row][NTOT] = x @ Wt + biasc ----------------
// 4 waves = 2x2 wave grid; wave tile = (BM/2)x32 via (BM/32)x2 16x16x32 frags.

template <int K, int NTOT, int BM>
DEV_INLINE void gemm_body(const ushort* __restrict__ xb,
                          const ushort* __restrict__ Wt,
                          const float* __restrict__ biasc,
                          ushort* __restrict__ Pb,
                          int Mrows, int bx, int by, int t,
                          ushort (*As)[40]) {
    constexpr int FI = BM / 32;
    const int lane = t & 63;
    const int wave = t >> 6;
    const int wr = wave >> 1, wc = wave & 1;
    const int row0 = bx * BM;
    const int col0 = by * 64;
    const int l15 = lane & 15;
    const int kg = lane >> 4;
    f32x4 acc[FI][2] = {};

    for (int k0 = 0; k0 < K; k0 += 32) {
        __syncthreads();
        if constexpr (BM == 64) {
            const int srow = t >> 2, sseg = (t & 3) * 8;
            uint4 a = {0, 0, 0, 0};
            const int gr = row0 + srow;
            if (gr < Mrows) a = *(const uint4*)&xb[(size_t)gr * K + k0 + sseg];
            *(uint4*)&As[srow][sseg] = a;
        } else {
            const int srow = t >> 1, sseg = (t & 1) * 16;
            uint4 a0 = {0, 0, 0, 0}, a1 = {0, 0, 0, 0};
            const int gr = row0 + srow;
            if (gr < Mrows) {
                a0 = *(const uint4*)&xb[(size_t)gr * K + k0 + sseg];
                a1 = *(const uint4*)&xb[(size_t)gr * K + k0 + sseg + 8];
            }
            *(uint4*)&As[srow][sseg] = a0;
            *(uint4*)&As[srow][sseg + 8] = a1;
        }
        __syncthreads();
        bf16x8 af[FI], bfr[2];
#pragma unroll
        for (int fi = 0; fi < FI; fi++)
            af[fi] = *(const bf16x8*)&As[wr * (BM / 2) + fi * 16 + l15][kg * 8];
#pragma unroll
        for (int fj = 0; fj < 2; fj++) {
            const int c = col0 + wc * 32 + fj * 16 + l15;
            bfr[fj] = *(const bf16x8*)&Wt[(size_t)c * K + k0 + kg * 8];
        }
#pragma unroll
        for (int fi = 0; fi < FI; fi++)
#pragma unroll
            for (int fj = 0; fj < 2; fj++)
                acc[fi][fj] = __builtin_amdgcn_mfma_f32_16x16x32_bf16(
                    af[fi], bfr[fj], acc[fi][fj], 0, 0, 0);
    }
    // D layout (m89-verified): col = lane&15, row = (lane>>4)*4 + reg
#pragma unroll
    for (int fi = 0; fi < FI; fi++) {
#pragma unroll
        for (int fj = 0; fj < 2; fj++) {
            const int c = col0 + wc * 32 + fj * 16 + l15;
            const float bc = biasc[c];
#pragma unroll
            for (int r = 0; r < 4; r++) {
                const int row = row0 + wr * (BM / 2) + fi * 16 + kg * 4 + r;
                if (row < Mrows) Pb[(size_t)row * NTOT + c] = f2bf(acc[fi][fj][r] + bc);
            }
        }
    }
}

template <int K, int NTOT, int BM>
__global__ __launch_bounds__(256) void k_gemm(const ushort* __restrict__ xb,
                                              const ushort* __restrict__ Wt,
                                              const float* __restrict__ biasc,
                                              ushort* __restrict__ Pb, int Mrows) {
    __shared__ ushort As[BM][40];
    gemm_body<K, NTOT, BM>(xb, Wt, biasc, Pb, Mrows, blockIdx.x, blockIdx.y,
                           threadIdx.x, As);
}

// ---------------- fat prep kernel: [rank | wprep | bias | latent] ----------------
// d-col = Wa-Wb, b-col = Wb (rows [K,2K) of source W).

DEV_INLINE float wsrc(const float* W, int K, int C, int k, int c, bool isB) {
    return isB ? W[(size_t)(K + k) * C + c]
               : W[(size_t)k * C + c] - W[(size_t)(K + k) * C + c];
}

__global__ __launch_bounds__(256) void k_prep(
        const int* __restrict__ g0, const int* __restrict__ g1, const int* __restrict__ g2,
        int* __restrict__ cursor, int* __restrict__ bcur, int* __restrict__ rnk,
        const float* Wb, const float* l0_W1, const float* l0_W2, const float* l0_Wsk,
        const float* l1_W1, const float* l1_W2, const float* l1_Wsk, const float* Wf,
        ushort* Wt0, ushort* WtP0, ushort* Wt2, ushort* WtP1, ushort* Wt4, ushort* Wt5,
        const float* bb, const float* l0_b1, const float* l0_b2, const float* l0_bsk,
        const float* l1_b1, const float* l1_b2, const float* l1_bsk, const float* bf_,
        float* biasc0, float* biascP0, float* biasc2, float* biascP1,
        float* biasc4, float* biasc5,
        const float* z, const float* W_up1, const float* b_up1,
        const float* W_up2, const float* b_up2, ushort* x0b) {
    __shared__ float col[64];
    const int bid = blockIdx.x;
    const int t = threadIdx.x;

    if (bid < RB) {
        // ---- rank: one atomic/edge, rank+front-bit stored coalesced ----
        const int q = bid * 256 + t;
        int4 sv, dv; int mod_, nb_, thr_, ebase;
        if (q < Q0) {
            sv = *(const int4*)&g0[q * 4]; dv = *(const int4*)&g0[E0n + q * 4];
            mod_ = N0n; nb_ = 0; thr_ = N1n; ebase = q * 4;
        } else if (q < Q0 + Q1) {
            const int lq = q - Q0;
            sv = *(const int4*)&g1[lq * 4]; dv = *(const int4*)&g1[E1n + lq * 4];
            mod_ = N1n; nb_ = N0n; thr_ = N2n; ebase = E0n + lq * 4;
        } else if (q < QT) {
            const int lq = q - Q0 - Q1;
            sv = *(const int4*)&g2[lq * 4]; dv = *(const int4*)&g2[E2n + lq * 4];
            mod_ = N2n; nb_ = N0n + N1n; thr_ = N2n; ebase = E0n + E1n + lq * 4;
        } else return;
        const int ss[4] = {sv.x, sv.y, sv.z, sv.w};
        const int dd[4] = {dv.x, dv.y, dv.z, dv.w};
        int out[4];
#pragma unroll
        for (int i = 0; i < 4; i++) {
            const int src = ss[i] % mod_;
            const int gd = nb_ + dd[i] % mod_;
            const bool front = src < thr_;
            const int r = front ? atomicAdd(&cursor[gd], 1) : atomicAdd(&bcur[gd], 1);
            out[i] = r | (front ? (1 << 30) : 0);
        }
        *(int4*)&rnk[ebase] = int4{out[0], out[1], out[2], out[3]};
    } else if (bid < RB + WB) {
        // ---- wprep: 6 sets x 32 blocks, grid-stride ----
        const int wb = bid - RB;
        const int set = wb >> 5, blk = wb & 31;
        if (set == 0) {          // conv1: [512][128] (d256|b256) from Wb C=256
            for (int idx = blk * 256 + t; idx < 512 * 128; idx += 32 * 256) {
                const int n = idx / 128, k = idx % 128;
                Wt0[idx] = f2bf(n < 256 ? wsrc(Wb, 128, 256, k, n, false)
                                        : wsrc(Wb, 128, 256, k, n - 256, true));
            }
        } else if (set == 1) {   // pairL0: [384][256] (l0W1 d64|b64, l0Wsk d128|b128)
            for (int idx = blk * 256 + t; idx < 384 * 256; idx += 32 * 256) {
                const int n = idx / 256, k = idx % 256;
                float v;
                if (n < 64)       v = wsrc(l0_W1, 256, 64, k, n, false);
                else if (n < 128) v = wsrc(l0_W1, 256, 64, k, n - 64, true);
                else if (n < 256) v = wsrc(l0_Wsk, 256, 128, k, n - 128, false);
                else              v = wsrc(l0_Wsk, 256, 128, k, n - 256, true);
                WtP0[idx] = f2bf(v);
            }
        } else if (set == 2) {   // l0_W2: [256][64] (d128|b128)
            for (int idx = blk * 256 + t; idx < 256 * 64; idx += 32 * 256) {
                const int n = idx / 64, k = idx % 64;
                Wt2[idx] = f2bf(n < 128 ? wsrc(l0_W2, 64, 128, k, n, false)
                                        : wsrc(l0_W2, 64, 128, k, n - 128, true));
            }
        } else if (set == 3) {   // pairL1: [256][128] (l1W1 d64|b64, l1Wsk d64|b64)
            for (int idx = blk * 256 + t; idx < 256 * 128; idx += 32 * 256) {
                const int n = idx / 128, k = idx % 128;
                float v;
                if (n < 64)       v = wsrc(l1_W1, 128, 64, k, n, false);
                else if (n < 128) v = wsrc(l1_W1, 128, 64, k, n - 64, true);
                else if (n < 192) v = wsrc(l1_Wsk, 128, 64, k, n - 128, false);
                else              v = wsrc(l1_Wsk, 128, 64, k, n - 192, true);
                WtP1[idx] = f2bf(v);
            }
        } else if (set == 4) {   // l1_W2: [128][64]
            for (int idx = blk * 256 + t; idx < 128 * 64; idx += 32 * 256) {
                const int n = idx / 64, k = idx % 64;
                Wt4[idx] = f2bf(n < 64 ? wsrc(l1_W2, 64, 64, k, n, false)
                                       : wsrc(l1_W2, 64, 64, k, n - 64, true));
            }
        } else {                 // final: [128][64]
            for (int idx = blk * 256 + t; idx < 128 * 64; idx += 32 * 256) {
                const int n = idx / 64, k = idx % 64;
                Wt5[idx] = f2bf(n < 64 ? wsrc(Wf, 64, 64, k, n, false)
                                       : wsrc(Wf, 64, 64, k, n - 64, true));
            }
        }
    } else if (bid == RB + WB) {
        // ---- concat bias buffers (0 in V regions) ----
        for (int i = t; i < 512; i += 256) biasc0[i] = i < 256 ? bb[i] : 0.f;
        for (int i = t; i < 384; i += 256)
            biascP0[i] = i < 64 ? l0_b1[i] : (i < 128 ? 0.f : (i < 256 ? l0_bsk[i - 128] : 0.f));
        for (int i = t; i < 256; i += 256) biasc2[i] = i < 128 ? l0_b2[i] : 0.f;
        for (int i = t; i < 256; i += 256)
            biascP1[i] = i < 64 ? l1_b1[i] : (i < 128 ? 0.f : (i < 192 ? l1_bsk[i - 128] : 0.f));
        for (int i = t; i < 128; i += 256) biasc4[i] = i < 64 ? l1_b2[i] : 0.f;
        for (int i = t; i < 128; i += 256) biasc5[i] = i < 64 ? bf_[i] : 0.f;
    } else {
        // ---- latent MLP: z -> x0 bf16 [12500][128] ----
        const int lb = bid - RB - WB - 1;
        const int b = t >> 7, l = t & 127;
        const float zv = z[b * 128 + l];
        float h1[64];
#pragma unroll
        for (int k = 0; k < 64; k++) h1[k] = lrelu(zv * W_up1[k] + b_up1[k]);
        for (int nn = 0; nn < 8; nn++) {
            const int n = lb * 8 + nn;
            if (n >= N2n) break;
            if (t < 64) col[t] = W_up2[t * N2n + n];
            __syncthreads();
            float s = b_up2[n];
#pragma unroll
            for (int k = 0; k < 64; k++) s += h1[k] * col[k];
            x0b[((size_t)n * Bn + b) * 128 + l] = f2bf(s);
            __syncthreads();
        }
    }
}

// ---------------- fat kernel: [fill2 | conv1 GEMM] ----------------

__global__ __launch_bounds__(256) void k_fill_conv(
        const int* __restrict__ g0, const int* __restrict__ g1, const int* __restrict__ g2,
        const int* __restrict__ offsets, const int* __restrict__ rnk, int* __restrict__ csr,
        const ushort* __restrict__ x0b, const ushort* __restrict__ Wt0,
        const float* __restrict__ biasc0, ushort* __restrict__ conv1P) {
    __shared__ ushort As[64][40];
    const int bid = blockIdx.x;
    const int t = threadIdx.x;
    if (bid < FB) {
        const int q = bid * 256 + t;
        int4 sv, dv; int mod_, nb_, ebase;
        if (q < Q0) {
            sv = *(const int4*)&g0[q * 4]; dv = *(const int4*)&g0[E0n + q * 4];
            mod_ = N0n; nb_ = 0; ebase = q * 4;
        } else if (q < Q0 + Q1) {
            const int lq = q - Q0;
            sv = *(const int4*)&g1[lq * 4]; dv = *(const int4*)&g1[E1n + lq * 4];
            mod_ = N1n; nb_ = N0n; ebase = E0n + lq * 4;
        } else if (q < QT) {
            const int lq = q - Q0 - Q1;
            sv = *(const int4*)&g2[lq * 4]; dv = *(const int4*)&g2[E2n + lq * 4];
            mod_ = N2n; nb_ = N0n + N1n; ebase = E0n + E1n + lq * 4;
        } else return;
        const int4 rv = *(const int4*)&rnk[ebase];
        const int ss[4] = {sv.x, sv.y, sv.z, sv.w};
        const int dd[4] = {dv.x, dv.y, dv.z, dv.w};
        const int rr[4] = {rv.x, rv.y, rv.z, rv.w};
#pragma unroll
        for (int i = 0; i < 4; i++) {
            const int src = ss[i] % mod_;
            const int gd = nb_ + dd[i] % mod_;
            const int r = rr[i] & 0x3FFFFFFF;
            const bool front = (rr[i] >> 30) & 1;
            const int pos = front ? offsets[gd] + r : offsets[gd + 1] - 1 - r;
            if (pos >= 0 && pos < ET) csr[pos] = src;
        }
    } else {
        const int gid = bid - FB;                 // conv1: 196 x 8
        gemm_body<128, 512, 64>(x0b, Wt0, biasc0, conv1P, N2n * Bn,
                                gid % 196, gid / 196, t, As);
    }
}

// ---------------- dense edge agg (strided): out[i] = mean_j relu(u_i + v_j) -------
// COUT2 = channels/node, W = containing matrix width; co maps c8 -> element off.

template <int COUT2, int CAP, int W>
__global__ __launch_bounds__(256) void k_edge_agg(const ushort* __restrict__ Ub,
                                                  const ushort* __restrict__ Vb,
                                                  const int* __restrict__ offsets,
                                                  const int* __restrict__ csr,
                                                  int nbase, int nnodes,
                                                  ushort* __restrict__ outb) {
    constexpr int H = COUT2 / 2;
    constexpr int TPN = COUT2 / 8;
    constexpr int NPB = 256 / TPN;
    constexpr int NS = 2 * W;
    __shared__ int soff[NPB + 1];
    __shared__ int scsr[CAP];
    const int t = threadIdx.x;
    const int n0 = blockIdx.x * NPB;
    if (t <= NPB) {
        const int idx = min(n0 + t, nnodes);
        soff[t] = max(0, min(offsets[nbase + idx], ET));
    }
    __syncthreads();
    const int base = soff[0];
    const int span = soff[NPB] - base;
    const int tot = min(span, CAP);
    for (int k = t; k < tot; k += 256) scsr[k] = csr[base + k];
    __syncthreads();
    const bool allin = span <= CAP;

    const int sub = t / TPN;
    const int c8 = (t % TPN) * 8;
    const int co = (c8 & (H - 1)) + (c8 >= H ? W : 0);
    const int i = n0 + sub;
    if (i >= nnodes) return;
    const int beg = soff[sub];
    const int end = max(soff[sub + 1], beg);
    float u[8], acc[8] = {};
    unpack_bf8(u, *(const uint4*)&Ub[(size_t)i * NS + co]);
    if (allin) {
        int o = beg - base;
        const int oend = end - base;
        for (; o + 4 <= oend; o += 4) {
            const int j0 = scsr[o], j1 = scsr[o + 1], j2 = scsr[o + 2], j3 = scsr[o + 3];
            const uint4 w0 = *(const uint4*)&Vb[(size_t)j0 * NS + co];
            const uint4 w1 = *(const uint4*)&Vb[(size_t)j1 * NS + co];
            const uint4 w2 = *(const uint4*)&Vb[(size_t)j2 * NS + co];
            const uint4 w3 = *(const uint4*)&Vb[(size_t)j3 * NS + co];
            acc_bf8(acc, u, w0); acc_bf8(acc, u, w1);
            acc_bf8(acc, u, w2); acc_bf8(acc, u, w3);
        }
        for (; o < oend; ++o)
            acc_bf8(acc, u, *(const uint4*)&Vb[(size_t)scsr[o] * NS + co]);
    } else {
        for (int e = beg; e < end; ++e)
            acc_bf8(acc, u, *(const uint4*)&Vb[(size_t)csr[e] * NS + co]);
    }
    const int dg = end - beg;
    const float inv = 1.f / (float)(dg > 0 ? dg : 1);
    uint4 o;
    o.x = pack2(acc[0] * inv, acc[1] * inv);
    o.y = pack2(acc[2] * inv, acc[3] * inv);
    o.z = pack2(acc[4] * inv, acc[5] * inv);
    o.w = pack2(acc[6] * inv, acc[7] * inv);
    *(uint4*)&outb[(size_t)i * COUT2 + c8] = o;
}

// ---------------- fused dual agg (strided U2/V2 and Usk/Vsk) ----------------

template <int COUT2, int CAP, int W2, int WSK>
__global__ __launch_bounds__(256) void k_edge_agg_fused(const ushort* __restrict__ U2b,
                                                        const ushort* __restrict__ V2b,
                                                        const ushort* __restrict__ Uskb,
                                                        const ushort* __restrict__ Vskb,
                                                        const float* __restrict__ b2,
                                                        const float* __restrict__ bsk,
                                                        const int* __restrict__ offsets,
                                                        const int* __restrict__ vcnt,
                                                        const int* __restrict__ csr,
                                                        int nbase, int nnodes, int nnz,
                                                        ushort* __restrict__ outb) {
    constexpr int H = COUT2 / 2;
    constexpr int TPN = COUT2 / 8;
    constexpr int NPB = 256 / TPN;
    constexpr int NS2 = 2 * W2, NSS = 2 * WSK;
    __shared__ int soff[NPB + 1];
    __shared__ int svc[NPB];
    __shared__ int scsr[CAP];
    const int t = threadIdx.x;
    const int n0 = blockIdx.x * NPB;
    if (t <= NPB) {
        const int idx = min(n0 + t, nnodes);
        soff[t] = max(0, min(offsets[nbase + idx], ET));
    }
    if (t < NPB) svc[t] = (n0 + t < nnodes) ? vcnt[nbase + n0 + t] : 0;
    __syncthreads();
    const int base = soff[0];
    const int span = soff[NPB] - base;
    const int tot = min(span, CAP);
    for (int k = t; k < tot; k += 256) scsr[k] = csr[base + k];
    __syncthreads();
    const bool allin = span <= CAP;

    const int sub = t / TPN;
    const int c8 = (t % TPN) * 8;
    const int co2 = (c8 & (H - 1)) + (c8 >= H ? W2 : 0);
    const int cos = (c8 & (H - 1)) + (c8 >= H ? WSK : 0);
    const int i = n0 + sub;
    if (i >= nnodes) return;
    const int beg = soff[sub];
    const int end = max(soff[sub + 1], beg);
    const int dg = end - beg;
    const int vc = max(0, min(svc[sub], dg));
    const int cb = c8 & (H - 1);
    float u2[8], usk[8];
    if (i < nnz) {
        unpack_bf8(u2,  *(const uint4*)&U2b[(size_t)i * NS2 + co2]);
        unpack_bf8(usk, *(const uint4*)&Uskb[(size_t)i * NSS + cos]);
    } else {
        *(float4*)&u2[0]  = *(const float4*)&b2[cb];
        *(float4*)&u2[4]  = *(const float4*)&b2[cb + 4];
        *(float4*)&usk[0] = *(const float4*)&bsk[cb];
        *(float4*)&usk[4] = *(const float4*)&bsk[cb + 4];
    }
    float a2[8] = {}, ask[8] = {};
    if (allin) {
        int o = beg - base;
        const int oend = o + vc;
        for (; o + 2 <= oend; o += 2) {
            const int j0 = scsr[o], j1 = scsr[o + 1];
            const uint4 p0 = *(const uint4*)&V2b[(size_t)j0 * NS2 + co2];
            const uint4 p1 = *(const uint4*)&V2b[(size_t)j1 * NS2 + co2];
            const uint4 q0 = *(const uint4*)&Vskb[(size_t)j0 * NSS + cos];
            const uint4 q1 = *(const uint4*)&Vskb[(size_t)j1 * NSS + cos];
            acc_bf8(a2, u2, p0); acc_bf8(a2, u2, p1);
            acc_bf8(ask, usk, q0); acc_bf8(ask, usk, q1);
        }
        for (; o < oend; ++o) {
            const int j = scsr[o];
            acc_bf8(a2, u2, *(const uint4*)&V2b[(size_t)j * NS2 + co2]);
            acc_bf8(ask, usk, *(const uint4*)&Vskb[(size_t)j * NSS + cos]);
        }
    } else {
        for (int e = beg; e < beg + vc; ++e) {
            const int j = csr[e];
            acc_bf8(a2, u2, *(const uint4*)&V2b[(size_t)j * NS2 + co2]);
            acc_bf8(ask, usk, *(const uint4*)&Vskb[(size_t)j * NSS + cos]);
        }
    }
    const int cnt = dg - vc;
    if (cnt > 0) {
        const float fc = (float)cnt;
#pragma unroll
        for (int k = 0; k < 8; k++) {
            a2[k]  += fc * fmaxf(u2[k], 0.f);
            ask[k] += fc * fmaxf(usk[k], 0.f);
        }
    }
    const float inv = 1.f / (float)(dg > 0 ? dg : 1);
    float ov[8];
#pragma unroll
    for (int k = 0; k < 8; k++) ov[k] = lrelu((a2[k] + ask[k]) * inv);
    uint4 o;
    o.x = pack2(ov[0], ov[1]); o.y = pack2(ov[2], ov[3]);
    o.z = pack2(ov[4], ov[5]); o.w = pack2(ov[6], ov[7]);
    *(uint4*)&outb[(size_t)i * COUT2 + c8] = o;
}

// ---------------- fused final agg + decoder MLP + LayerNorm(3) ----------------
// U/V from finalP (W=128): co = (c8&63) + (c8>=64 ? 128 : 0), node stride 256.

__global__ __launch_bounds__(256) void k_agg_dec(const ushort* __restrict__ Ub,
                                                 const ushort* __restrict__ Vb,
                                                 const int* __restrict__ offsets,
                                                 const int* __restrict__ csr,
                                                 const float* __restrict__ Wd1,
                                                 const float* __restrict__ bd1,
                                                 const float* __restrict__ Wd2,
                                                 const float* __restrict__ bd2,
                                                 const float* __restrict__ gamma,
                                                 const float* __restrict__ beta,
                                                 float* __restrict__ out) {
    constexpr int CAP = 768;
    __shared__ float w1[2048];
    __shared__ float w2[96];
    __shared__ float sb1[32], sb2[3], sg[3], sbt[3];
    __shared__ float xs[32 * 66];
    __shared__ float hs[32][33];
    __shared__ int soff[17];
    __shared__ int scsr[CAP];
    const int t = threadIdx.x;
    for (int i = t; i < 2048; i += 256) w1[i] = Wd1[i];
    if (t < 96) w2[t] = Wd2[t];
    if (t < 32) sb1[t] = bd1[t];
    if (t < 3) { sb2[t] = bd2[t]; sg[t] = gamma[t]; sbt[t] = beta[t]; }

    const int n0 = blockIdx.x * 16;
    if (t <= 16) {
        const int idx = min(n0 + t, N0n);
        soff[t] = max(0, min(offsets[idx], ET));
    }
    __syncthreads();
    const int base = soff[0];
    const int span = soff[16] - base;
    const int tot = min(span, CAP);
    for (int k = t; k < tot; k += 256) scsr[k] = csr[base + k];
    __syncthreads();
    const bool allin = span <= CAP;

    const int sub = t >> 4;
    const int c8 = (t & 15) * 8;
    const int co = (c8 & 63) + (c8 >= 64 ? 128 : 0);
    const int i0 = n0 + sub;
    float r[8] = {};
    if (i0 < N0n) {
        const int beg = soff[sub];
        const int end = max(soff[sub + 1], beg);
        float u[8], acc[8] = {};
        unpack_bf8(u, *(const uint4*)&Ub[(size_t)i0 * 256 + co]);
        if (allin) {
            int o = beg - base;
            const int oend = end - base;
            for (; o + 4 <= oend; o += 4) {
                const int j0 = scsr[o], j1 = scsr[o + 1], j2 = scsr[o + 2], j3 = scsr[o + 3];
                const uint4 w0 = *(const uint4*)&Vb[(size_t)j0 * 256 + co];
                const uint4 w1v = *(const uint4*)&Vb[(size_t)j1 * 256 + co];
                const uint4 w2v = *(const uint4*)&Vb[(size_t)j2 * 256 + co];
                const uint4 w3 = *(const uint4*)&Vb[(size_t)j3 * 256 + co];
                acc_bf8(acc, u, w0); acc_bf8(acc, u, w1v);
                acc_bf8(acc, u, w2v); acc_bf8(acc, u, w3);
            }
            for (; o < oend; ++o)
                acc_bf8(acc, u, *(const uint4*)&Vb[(size_t)scsr[o] * 256 + co]);
        } else {
            for (int e = beg; e < end; ++e)
                acc_bf8(acc, u, *(const uint4*)&Vb[(size_t)csr[e] * 256 + co]);
        }
        const int dg = end - beg;
        const float inv = 1.f / (float)(dg > 0 ? dg : 1);
#pragma unroll
        for (int k = 0; k < 8; k++) r[k] = acc[k] * inv;
    }
    {
        const int rrow = sub * 2 + (c8 >> 6);
        const int rk = c8 & 63;
        float* xp = &xs[rrow * 66 + rk];
#pragma unroll
        for (int k = 0; k < 8; k++) xp[k] = r[k];
    }
    __syncthreads();

    const int drow = t >> 3;
    const int l8 = t & 7;
    float h1[4] = {sb1[l8], sb1[l8 + 8], sb1[l8 + 16], sb1[l8 + 24]};
    const float* xrow = &xs[drow * 66];
#pragma unroll 8
    for (int k = 0; k < 64; k++) {
        const float xk = xrow[k];
        h1[0] += xk * w1[k * 32 + l8];
        h1[1] += xk * w1[k * 32 + l8 + 8];
        h1[2] += xk * w1[k * 32 + l8 + 16];
        h1[3] += xk * w1[k * 32 + l8 + 24];
    }
    hs[drow][l8]      = lrelu(h1[0]);
    hs[drow][l8 + 8]  = lrelu(h1[1]);
    hs[drow][l8 + 16] = lrelu(h1[2]);
    hs[drow][l8 + 24] = lrelu(h1[3]);
    __syncthreads();

    if (t < 32) {
        const int node = t >> 1, b = t & 1;
        const int n = n0 + node;
        if (n < N0n) {
            float h2[3];
#pragma unroll
            for (int j = 0; j < 3; j++) {
                float s = sb2[j];
#pragma unroll
                for (int c = 0; c < 32; c++) s += hs[t][c] * w2[c * 3 + j];
                h2[j] = s;
            }
            const float mu = (h2[0] + h2[1] + h2[2]) * (1.f / 3.f);
            const float d0 = h2[0] - mu, d1 = h2[1] - mu, d2 = h2[2] - mu;
            const float var = (d0 * d0 + d1 * d1 + d2 * d2) * (1.f / 3.f);
            const float inv = rsqrtf(var + 1e-5f);
            const size_t ob = (size_t)b * N0n * 3 + (size_t)n * 3;
            out[ob + 0] = d0 * inv * sg[0] + sbt[0];
            out[ob + 1] = d1 * inv * sg[1] + sbt[1];
            out[ob + 2] = d2 * inv * sg[2] + sbt[2];
        }
    }
}

// ---------------- launch ----------------

extern "C" void kernel_launch(void* const* d_in, const int* in_sizes, int n_in,
                              void* d_out, int out_size, void* d_ws, size_t ws_size,
                              hipStream_t stream) {
    (void)in_sizes; (void)n_in; (void)out_size; (void)ws_size;
    const float* z   = (const float*)d_in[0];
    const int* g0    = (const int*)d_in[1];
    const int* g1    = (const int*)d_in[2];
    const int* g2    = (const int*)d_in[3];
    const float* W_up1 = (const float*)d_in[6];
    const float* b_up1 = (const float*)d_in[7];
    const float* W_up2 = (const float*)d_in[8];
    const float* b_up2 = (const float*)d_in[9];
    const float* Wb    = (const float*)d_in[10];
    const float* bb    = (const float*)d_in[11];
    const float* l0_W1 = (const float*)d_in[12];
    const float* l0_b1 = (const float*)d_in[13];
    const float* l0_W2 = (const float*)d_in[14];
    const float* l0_b2 = (const float*)d_in[15];
    const float* l0_Wsk = (const float*)d_in[16];
    const float* l0_bsk = (const float*)d_in[17];
    const float* l1_W1 = (const float*)d_in[18];
    const float* l1_b1 = (const float*)d_in[19];
    const float* l1_W2 = (const float*)d_in[20];
    const float* l1_b2 = (const float*)d_in[21];
    const float* l1_Wsk = (const float*)d_in[22];
    const float* l1_bsk = (const float*)d_in[23];
    const float* Wf    = (const float*)d_in[24];
    const float* bf_   = (const float*)d_in[25];
    const float* Wd1   = (const float*)d_in[26];
    const float* bd1   = (const float*)d_in[27];
    const float* Wd2   = (const float*)d_in[28];
    const float* bd2   = (const float*)d_in[29];
    const float* gamma = (const float*)d_in[30];
    const float* beta  = (const float*)d_in[31];

    char* p = (char*)d_ws;
    auto alloc = [&](size_t bytes) -> char* {
        char* r = p; p += (bytes + 255) & ~(size_t)255; return r;
    };
    int* offsets  = (int*)alloc((size_t)(NT + 1) * 4);
    int* partials = (int*)alloc((size_t)NCHUNK * 4);
    int* degcur   = (int*)alloc((size_t)2 * NT * 4);
    int* cursor = degcur; int* bcur = degcur + NT;
    int* csr = (int*)alloc((size_t)ET * 4);
    int* rnk = (int*)alloc((size_t)ET * 4);

    // bf16 weight buffers + concat bias buffers
    ushort* Wt0  = (ushort*)alloc(512 * 128 * 2);
    ushort* WtP0 = (ushort*)alloc(384 * 256 * 2);
    ushort* Wt2  = (ushort*)alloc(256 * 64 * 2);
    ushort* WtP1 = (ushort*)alloc(256 * 128 * 2);
    ushort* Wt4  = (ushort*)alloc(128 * 64 * 2);
    ushort* Wt5  = (ushort*)alloc(128 * 64 * 2);
    float* biasc0  = (float*)alloc(512 * 4);
    float* biascP0 = (float*)alloc(384 * 4);
    float* biasc2  = (float*)alloc(256 * 4);
    float* biascP1 = (float*)alloc(256 * 4);
    float* biasc4  = (float*)alloc(128 * 4);
    float* biasc5  = (float*)alloc(128 * 4);

    // pooled slabs: A,B,C = 8 granules of M1 = 1.6M floats (6.4MB) each.
    constexpr size_t SLOT = (size_t)N0n * Bn * 64;   // 12.8M floats
    constexpr size_t M1 = 1600000;
    float* A = (float*)alloc(SLOT * 4);
    float* B = (float*)alloc(SLOT * 4);
    float* C = (float*)alloc(SLOT * 4);

    // placements (lifetimes verified r12):
    ushort* x0b     = (ushort*)A;                    // 12500x128
    ushort* conv1P  = (ushort*)(A + 1 * M1);         // 12500x512
    ushort* xc1b    = (ushort*)(A + 3 * M1);         // 6250x512 compact
    ushort* pairL0P = (ushort*)(A + 4 * M1);         // 12500x384
    ushort* t1b     = (ushort*)(A + 6 * M1);         // 6250x128
    ushort* l0W2P   = (ushort*)(A + 7 * M1);         // 12500x256
    ushort* x1b     = (ushort*)B;                    // 25000x256 compact
    ushort* pairL1P = (ushort*)(B + 2 * M1);         // 50000x256
    ushort* t2b     = (ushort*)(B + 6 * M1);         // 25000x128 compact
    ushort* l1W2P   = (ushort*)C;                    // 50000x128
    ushort* x2b     = (ushort*)(C + 2 * M1);         // 100000x128 compact
    ushort* finalP  = (ushort*)A;                    // 200000x128 (A fully dead)

    const int nb2 = N0n + N1n;
    const int nb1 = N0n;

    // 1. zero counters
    hipMemsetAsync(degcur, 0, (size_t)2 * NT * 4, stream);
    // 2. fat prep: [rank | wprep | bias | latent]
    k_prep<<<RB + WB + 1 + LB, 256, 0, stream>>>(
        g0, g1, g2, cursor, bcur, rnk,
        Wb, l0_W1, l0_W2, l0_Wsk, l1_W1, l1_W2, l1_Wsk, Wf,
        Wt0, WtP0, Wt2, WtP1, Wt4, Wt5,
        bb, l0_b1, l0_b2, l0_bsk, l1_b1, l1_b2, l1_bsk, bf_,
        biasc0, biascP0, biasc2, biascP1, biasc4, biasc5,
        z, W_up1, b_up1, W_up2, b_up2, x0b);
    // 3-4. scan
    k_scan1<<<NCHUNK, 256, 0, stream>>>(cursor, bcur, offsets, partials);
    k_scan3<<<(NT + 255) / 256, 256, 0, stream>>>(partials, offsets);
    // 5. fat: [fill2 | conv1 GEMM]
    k_fill_conv<<<FB + 196 * 8, 256, 0, stream>>>(g0, g1, g2, offsets, rnk, csr,
                                                  x0b, Wt0, biasc0, conv1P);
    // 6. agg g2 (conv1): COUT2=512, W=512 -> xc1b
    k_edge_agg<512, 256, 512><<<(N2n + 3) / 4, 256, 0, stream>>>(
        conv1P, conv1P + 256, offsets, csr, nb2, N2n, xc1b);
    // 7. pair GEMM l0 (l0_W1 + skip0): xc1b -> pairL0P [12500][384]
    k_gemm<256, 384, 64><<<dim3(196, 6), 256, 0, stream>>>(xc1b, WtP0, biascP0,
                                                           pairL0P, N2n * Bn);
    // 8. agg t1 (g2): U/V cols 0-63/64-127 of pairL0P (W=384) -> t1b
    k_edge_agg<128, 768, 384><<<(N2n + 15) / 16, 256, 0, stream>>>(
        pairL0P, pairL0P + 64, offsets, csr, nb2, N2n, t1b);
    // 9. l0_W2: t1b -> l0W2P [12500][256]
    k_gemm<64, 256, 64><<<dim3(196, 4), 256, 0, stream>>>(t1b, Wt2, biasc2,
                                                          l0W2P, N2n * Bn);
    // 10. fused g1: U2/V2 from l0W2P (W=256), Usk/Vsk cols 128/256 of pairL0P
    k_edge_agg_fused<256, 512, 256, 384><<<(N1n + 7) / 8, 256, 0, stream>>>(
        l0W2P, l0W2P + 128, pairL0P + 128, pairL0P + 256,
        l0_b2, l0_bsk, offsets, cursor, csr, nb1, N1n, N2n, x1b);
    // 11. pair GEMM l1 (l1_W1 + skip1): x1b -> pairL1P [50000][256]
    k_gemm<128, 256, 128><<<dim3(391, 4), 256, 0, stream>>>(x1b, WtP1, biascP1,
                                                            pairL1P, N1n * Bn);
    // 12. agg g1: U/V cols 0/64 of pairL1P (W=256) -> t2b
    k_edge_agg<128, 768, 256><<<(N1n + 15) / 16, 256, 0, stream>>>(
        pairL1P, pairL1P + 64, offsets, csr, nb1, N1n, t2b);
    // 13. l1_W2: t2b -> l1W2P [50000][128]
    k_gemm<64, 128, 128><<<dim3(391, 2), 256, 0, stream>>>(t2b, Wt4, biasc4,
                                                           l1W2P, N1n * Bn);
    // 14. fused g0: U2/V2 from l1W2P (W=128), Usk/Vsk cols 128/192 of pairL1P
    k_edge_agg_fused<128, 768, 128, 256><<<(N0n + 15) / 16, 256, 0, stream>>>(
        l1W2P, l1W2P + 64, pairL1P + 128, pairL1P + 192,
        l1_b2, l1_bsk, offsets, cursor, csr, 0, N0n, N1n, x2b);
    // 15. final conv: x2b -> finalP [200000][128] (U cols 0-63, V 64-127)
    k_gemm<64, 128, 128><<<dim3(1563, 2), 256, 0, stream>>>(x2b, Wt5, biasc5,
                                                            finalP, N0n * Bn);
    // 16. fused final agg + decoder + LN -> d_out
    k_agg_dec<<<(N0n + 15) / 16, 256, 0, stream>>>(finalP, finalP + 64, offsets, csr,
                                                   Wd1, bd1, Wd2, bd2, gamma, beta,
                                                   (float*)d_out);
}